// Round 6
// baseline (232.258 us; speedup 1.0000x reference)
//
#include <hip/hip_runtime.h>
#include <hip/hip_bf16.h>
#include <math.h>

#define HWX 16384   // 128*128 pixels per (b, channel) plane

typedef __attribute__((ext_vector_type(8))) short short8v;
typedef __attribute__((ext_vector_type(4))) float f32x4;

__device__ inline ushort f2bf(float x) {
    union { __hip_bfloat16 h; ushort u; } cv;
    cv.h = __float2bfloat16(x);
    return cv.u;
}

// ---------------------------------------------------------------------------
// Pack six 5x5-conv weight sets -> Wpk[oc][k] bf16, k = (ky*5+kx)*64 + ic.
//   oc 0..17 pc1 | 18..35 pc2 | 36..53 pc4 | 54..71 pc5 | 72..80 z | 81..89 m
//   | 90..95 zero.  bias fp32 in bpack[96].  Source OIHW: o*1600 + ic*25 + kyx.
// ---------------------------------------------------------------------------
__global__ __launch_bounds__(256) void packw_kernel(
    const float* __restrict__ w1, const float* __restrict__ b1,
    const float* __restrict__ w2, const float* __restrict__ b2,
    const float* __restrict__ w4, const float* __restrict__ b4,
    const float* __restrict__ w5, const float* __restrict__ b5,
    const float* __restrict__ wz, const float* __restrict__ bz,
    const float* __restrict__ wm, const float* __restrict__ bm,
    __hip_bfloat16* __restrict__ Wpk, float* __restrict__ bpack)
{
    const int idx = blockIdx.x * 256 + threadIdx.x;
    if (idx < 96) {
        const int o = idx; float v = 0.f;
        if      (o < 18) v = b1[o];
        else if (o < 36) v = b2[o - 18];
        else if (o < 54) v = b4[o - 36];
        else if (o < 72) v = b5[o - 54];
        else if (o < 81) v = bz[o - 72];
        else if (o < 90) v = bm[o - 81];
        bpack[o] = v;
    }
    if (idx < 96 * 1600) {
        const int o   = idx / 1600;
        const int k   = idx - o * 1600;
        const int kyx = k >> 6;
        const int ic  = k & 63;
        const int off = ic * 25 + kyx;
        float v = 0.f;
        if      (o < 18) v = w1[o * 1600 + off];
        else if (o < 36) v = w2[(o - 18) * 1600 + off];
        else if (o < 54) v = w4[(o - 36) * 1600 + off];
        else if (o < 72) v = w5[(o - 54) * 1600 + off];
        else if (o < 81) v = wz[(o - 72) * 1600 + off];
        else if (o < 90) v = wm[(o - 81) * 1600 + off];
        Wpk[idx] = __float2bfloat16(v);
    }
}

// ---------------------------------------------------------------------------
// offset_source -> channel-last bf16 with baked-in zero pad ring:
//   osT[b][yy:132][xx:132][c:64]
// ---------------------------------------------------------------------------
__global__ __launch_bounds__(256) void packosT_kernel(
    const float* __restrict__ src, __hip_bfloat16* __restrict__ osT)
{
    const int yy = blockIdx.x;
    const int b  = blockIdx.y;
    __hip_bfloat16* dst = osT + ((size_t)b * 132 + yy) * 132 * 64;
    for (int idx = threadIdx.x; idx < 132 * 64; idx += 256) {
        const int xx = idx >> 6;
        const int c  = idx & 63;
        float v = 0.f;
        if (yy >= 2 && yy < 130 && xx >= 2 && xx < 130)
            v = src[(((b << 6) + c) << 14) + ((yy - 2) << 7) + (xx - 2)];
        dst[idx] = __float2bfloat16(v);
    }
}

// ---------------------------------------------------------------------------
// MFMA conv: C[96][16384] = Wpk[96][1600] x im2col(osT), per batch.
// Pure-register MFMA, no LDS/barriers. Block 256 = 4 waves (32 oc x 32 px
// each); grid (128 rows, 2 b, 3 ocg).
// ---------------------------------------------------------------------------
__global__ __launch_bounds__(256) void conv_mfma_kernel(
    const __hip_bfloat16* __restrict__ Wpk,   // [96][1600]
    const float* __restrict__ bpack,          // [96]
    const __hip_bfloat16* __restrict__ osT,   // [2][132][132][64]
    float* __restrict__ offs,                 // [4][2][18][HWX]
    float* __restrict__ zbuf,                 // [2][9][HWX]
    float* __restrict__ mbuf)                 // [2][9][HWX]
{
    const int y   = blockIdx.x;
    const int b   = blockIdx.y;
    const int ocg = blockIdx.z;
    const int t    = threadIdx.x;
    const int wv   = t >> 6;
    const int lane = t & 63;
    const int l15  = lane & 15;
    const int kgrp = lane >> 4;

    const ushort* W  = (const ushort*)Wpk;
    const ushort* ob = (const ushort*)osT + (size_t)b * (132 * 132 * 64);

    const int aoff0 = (ocg * 32 + l15) * 1600 + kgrp * 8;
    const int aoff1 = aoff0 + 16 * 1600;
    const int xloc0 = wv * 32 + l15;
    const int boff0 = (y * 132 + xloc0) * 64 + kgrp * 8;
    const int boff1 = boff0 + 16 * 64;

    f32x4 acc00 = {0.f,0.f,0.f,0.f}, acc01 = {0.f,0.f,0.f,0.f};
    f32x4 acc10 = {0.f,0.f,0.f,0.f}, acc11 = {0.f,0.f,0.f,0.f};

    #pragma unroll
    for (int ky = 0; ky < 5; ++ky)
    #pragma unroll
    for (int kx = 0; kx < 5; ++kx)
    #pragma unroll
    for (int ics = 0; ics < 2; ++ics) {
        const int uA = ((ky * 5 + kx) << 6) + (ics << 5);
        const int uB = ((ky * 132 + kx) << 6) + (ics << 5);
        const short8v a0 = *(const short8v*)(W  + aoff0 + uA);
        const short8v a1 = *(const short8v*)(W  + aoff1 + uA);
        const short8v b0 = *(const short8v*)(ob + boff0 + uB);
        const short8v b1 = *(const short8v*)(ob + boff1 + uB);
        acc00 = __builtin_amdgcn_mfma_f32_16x16x32_bf16(a0, b0, acc00, 0, 0, 0);
        acc01 = __builtin_amdgcn_mfma_f32_16x16x32_bf16(a0, b1, acc01, 0, 0, 0);
        acc10 = __builtin_amdgcn_mfma_f32_16x16x32_bf16(a1, b0, acc10, 0, 0, 0);
        acc11 = __builtin_amdgcn_mfma_f32_16x16x32_bf16(a1, b1, acc11, 0, 0, 0);
    }

    const int rowb = kgrp << 2;
    #pragma unroll
    for (int m = 0; m < 2; ++m)
    #pragma unroll
    for (int nf = 0; nf < 2; ++nf)
    #pragma unroll
    for (int r = 0; r < 4; ++r) {
        const f32x4 acc = (m == 0) ? (nf == 0 ? acc00 : acc01)
                                   : (nf == 0 ? acc10 : acc11);
        const int oc = ocg * 32 + m * 16 + rowb + r;
        if (oc < 90) {
            const int x = wv * 32 + nf * 16 + l15;
            const int p = (y << 7) + x;
            const float v = acc[r] + bpack[oc];
            if (oc < 72) {
                const int i = oc / 18, ch = oc - i * 18;
                offs[i * (2 * 18 * HWX) + (((b * 18) + ch) << 14) + p] = v;
            } else if (oc < 81) {
                zbuf[((b * 9 + (oc - 72)) << 14) + p] = 3.f / (1.f + expf(-v));
            } else {
                mbuf[((b * 9 + (oc - 81)) << 14) + p] = 1.f / (1.f + expf(-v));
            }
        }
    }
}

// ---------------------------------------------------------------------------
// Transpose img[b,c,y,x] fp32 -> imgT[img][b][p][c] bf16 (channel-last).
// ---------------------------------------------------------------------------
__global__ __launch_bounds__(256) void transpose_kernel(
    const float* __restrict__ i0, const float* __restrict__ i1,
    const float* __restrict__ i2, const float* __restrict__ i3,
    ushort* __restrict__ imgT)
{
    const int img = blockIdx.z;
    const int b   = blockIdx.y;
    const int p0  = blockIdx.x << 6;
    const float* src = (img == 0) ? i0 : (img == 1) ? i1 : (img == 2) ? i2 : i3;

    __shared__ float tile[64][65];
    const int t = threadIdx.x;
    const int pp = t & 63, c0 = t >> 6;
    #pragma unroll
    for (int k = 0; k < 16; ++k) {
        const int c = (k << 2) + c0;
        tile[c][pp] = src[(((b << 6) + c) << 14) + p0 + pp];
    }
    __syncthreads();
    // write bf16 pairs: c2 = t&31 -> channels 2c2,2c2+1; pl = t>>5 -> 8 px
    const int c2 = t & 31, pl = t >> 5;
    #pragma unroll
    for (int k = 0; k < 8; ++k) {
        const int pi = (k << 3) + pl;
        const uint packed = (uint)f2bf(tile[2 * c2][pi])
                          | ((uint)f2bf(tile[2 * c2 + 1][pi]) << 16);
        *(uint*)(imgT + ((size_t)(((img << 1) + b) << 14) + p0 + pi) * 64 + 2 * c2)
            = packed;
    }
}

// ---------------------------------------------------------------------------
// WcPk = flat bf16 cast of w_conv[64][64][9]  (A-operand layout [oc][cn]).
// ---------------------------------------------------------------------------
__global__ __launch_bounds__(256) void wcpk_kernel(
    const float* __restrict__ wc, __hip_bfloat16* __restrict__ WcPk)
{
    const int idx = blockIdx.x * 256 + threadIdx.x;
    if (idx < 36864) WcPk[idx] = __float2bfloat16(wc[idx]);
}

// ---------------------------------------------------------------------------
// Fused deform-sample + weighted-sum + MFMA contraction.
// One block = 16 consecutive pixels of one row of one batch.
//   A: 576 units -> tap indices + combined weights (LDS)
//   B: wide gather: lane=(px_sub 4, c4 16); 144 bf16x4 (8B) loads/wave,
//      in-lane corner accumulation -> s4[9] float4 -> contiguous bf16 LDS write
//   C: 4 waves x (16oc x 16px) MFMA, K=576: A=WcPk (global), B=s_sb (LDS)
// ---------------------------------------------------------------------------
__global__ __launch_bounds__(256) void fused_kernel(
    const float* __restrict__ offs,   // [4][2][18][HWX]
    const float* __restrict__ zbuf,   // [2][9][HWX]
    const float* __restrict__ mbuf,   // [2][9][HWX]
    const ushort* __restrict__ imgT,  // [4][2][HWX][64] bf16
    const __hip_bfloat16* __restrict__ WcPk,  // [64][576]
    float* __restrict__ out)          // [2][64][HWX]
{
    __shared__ __hip_bfloat16 s_sb[16 * 584];   // 18688 B
    __shared__ int4   s_ti4[16 * 36];           // 9216 B
    __shared__ float4 s_tw4[16 * 36];           // 9216 B

    const int t   = threadIdx.x;
    const int pid = blockIdx.x;
    const int b   = pid >> 10;
    const int rem = pid & 1023;
    const int h   = rem >> 3;
    const int w0p = (rem & 7) << 4;

    // ---- phase A: taps ----
    for (int u = t; u < 576; u += 256) {
        const int px   = u / 36;
        const int unit = u - px * 36;
        const int i    = unit / 9;
        const int n    = unit - i * 9;
        const int wcol = w0p + px;
        const int p    = (h << 7) + wcol;

        const float* ob = offs + i * (2 * 18 * HWX) + ((b * 18) << 14);
        const float ox = ob[(n << 14) + p];
        const float oy = ob[((n + 9) << 14) + p];
        const float z  = zbuf[((b * 9 + n) << 14) + p];
        const float mm = mbuf[((b * 9 + n) << 14) + p];

        const float zc0 = (i == 0) ? 1.f : 0.f;
        const float zc1 = (i == 0) ? (-11.f / 6.f) : (i == 1) ? 3.f
                         : (i == 2) ? -1.5f : (1.f / 3.f);
        const float zc2 = (i == 0) ? 1.f : (i == 1) ? -2.5f
                         : (i == 2) ? 2.f : -0.5f;
        const float zc3 = (i == 0) ? (-1.f / 6.f) : (i == 1) ? 0.5f
                         : (i == 2) ? -0.5f : (1.f / 6.f);
        const float zw   = zc0 + z * (zc1 + z * (zc2 + z * zc3));
        const float coef = zw * mm;

        const float pxf = (float)(h + n / 3) + ox;
        const float pyf = (float)(wcol + n % 3) + oy;
        const float flx = floorf(pxf), fly = floorf(pyf);
        const float qltx = fminf(fmaxf(flx, 0.f), 129.f);
        const float qrbx = fminf(fmaxf(flx + 1.f, 0.f), 129.f);
        const float qlty = fminf(fmaxf(fly, 0.f), 129.f);
        const float qrby = fminf(fmaxf(fly + 1.f, 0.f), 129.f);
        const float pxc = fminf(fmaxf(pxf, 0.f), 129.f);
        const float pyc = fminf(fmaxf(pyf, 0.f), 129.f);
        const float gxl = 1.f + (qltx - pxc);
        const float gxr = 1.f - (qrbx - pxc);
        const float gyl = 1.f + (qlty - pyc);
        const float gyr = 1.f - (qrby - pyc);
        const int ixl = (int)qltx, ixr = (int)qrbx;
        const int iyl = (int)qlty, iyr = (int)qrby;

        int4 ti; float4 tw;
        auto mk = [&](int qx, int qy, float g, int& ii, float& ww) {
            const bool valid = (qx >= 1) && (qx <= 128) && (qy >= 1) && (qy <= 128);
            ii = valid ? (((qx - 1) << 7) + (qy - 1)) : 0;
            ww = valid ? g * coef : 0.f;
        };
        mk(ixl, iyl, gxl * gyl, ti.x, tw.x);
        mk(ixr, iyr, gxr * gyr, ti.y, tw.y);
        mk(ixr, iyl, gxr * gyl, ti.z, tw.z);
        mk(ixl, iyr, gxl * gyr, ti.w, tw.w);
        s_ti4[u] = ti;
        s_tw4[u] = tw;
    }
    __syncthreads();

    // ---- phase B: wide gather ----
    const int lane = t & 63;
    const int wv   = t >> 6;
    const int c4   = lane & 15;
    const int pxs  = lane >> 4;
    const int px   = (wv << 2) + pxs;

    f32x4 s4[9];
    #pragma unroll
    for (int n = 0; n < 9; ++n) s4[n] = (f32x4){0.f, 0.f, 0.f, 0.f};

    const int tb = px * 36;
    const ushort* ibase = imgT + ((size_t)(b << 14) << 6) + (c4 << 2);
    #pragma unroll
    for (int i = 0; i < 4; ++i) {
        const ushort* ib = ibase + (size_t)i * (2u * HWX * 64);
        #pragma unroll
        for (int n = 0; n < 9; ++n) {
            const int4   ti = s_ti4[tb + i * 9 + n];
            const float4 tw = s_tw4[tb + i * 9 + n];
            {
                const uint2 v = *(const uint2*)(ib + ((size_t)ti.x << 6));
                s4[n].x = fmaf(tw.x, __uint_as_float(v.x << 16),        s4[n].x);
                s4[n].y = fmaf(tw.x, __uint_as_float(v.x & 0xffff0000u), s4[n].y);
                s4[n].z = fmaf(tw.x, __uint_as_float(v.y << 16),        s4[n].z);
                s4[n].w = fmaf(tw.x, __uint_as_float(v.y & 0xffff0000u), s4[n].w);
            }
            {
                const uint2 v = *(const uint2*)(ib + ((size_t)ti.y << 6));
                s4[n].x = fmaf(tw.y, __uint_as_float(v.x << 16),        s4[n].x);
                s4[n].y = fmaf(tw.y, __uint_as_float(v.x & 0xffff0000u), s4[n].y);
                s4[n].z = fmaf(tw.y, __uint_as_float(v.y << 16),        s4[n].z);
                s4[n].w = fmaf(tw.y, __uint_as_float(v.y & 0xffff0000u), s4[n].w);
            }
            {
                const uint2 v = *(const uint2*)(ib + ((size_t)ti.z << 6));
                s4[n].x = fmaf(tw.z, __uint_as_float(v.x << 16),        s4[n].x);
                s4[n].y = fmaf(tw.z, __uint_as_float(v.x & 0xffff0000u), s4[n].y);
                s4[n].z = fmaf(tw.z, __uint_as_float(v.y << 16),        s4[n].z);
                s4[n].w = fmaf(tw.z, __uint_as_float(v.y & 0xffff0000u), s4[n].w);
            }
            {
                const uint2 v = *(const uint2*)(ib + ((size_t)ti.w << 6));
                s4[n].x = fmaf(tw.w, __uint_as_float(v.x << 16),        s4[n].x);
                s4[n].y = fmaf(tw.w, __uint_as_float(v.x & 0xffff0000u), s4[n].y);
                s4[n].z = fmaf(tw.w, __uint_as_float(v.y << 16),        s4[n].z);
                s4[n].w = fmaf(tw.w, __uint_as_float(v.y & 0xffff0000u), s4[n].w);
            }
        }
    }

    // pack to bf16, write contiguous 36 ushorts (cn = (4*c4+j)*9 + n)
    ushort buf[36];
    #pragma unroll
    for (int j = 0; j < 4; ++j)
        #pragma unroll
        for (int n = 0; n < 9; ++n)
            buf[j * 9 + n] = f2bf(s4[n][j]);
    {
        uint2* dst = (uint2*)((char*)s_sb + px * 1168 + c4 * 72);
        const uint2* srcb = (const uint2*)buf;
        #pragma unroll
        for (int k = 0; k < 9; ++k) dst[k] = srcb[k];
    }
    __syncthreads();

    // ---- phase C: MFMA contraction, wave wv -> oc block wv*16 ----
    const int l15  = lane & 15;
    const int kgrp = lane >> 4;
    const ushort* Wb = (const ushort*)WcPk + (wv * 16 + l15) * 576 + kgrp * 8;
    const ushort* sb = (const ushort*)s_sb + l15 * 584 + kgrp * 8;

    f32x4 acc = {0.f, 0.f, 0.f, 0.f};
    #pragma unroll
    for (int ks = 0; ks < 18; ++ks) {
        const short8v a  = *(const short8v*)(Wb + ks * 32);
        const short8v bb = *(const short8v*)(sb + ks * 32);
        acc = __builtin_amdgcn_mfma_f32_16x16x32_bf16(a, bb, acc, 0, 0, 0);
    }

    const int p = (h << 7) + w0p + l15;
    #pragma unroll
    for (int r = 0; r < 4; ++r) {
        const int oc = wv * 16 + (kgrp << 2) + r;
        out[(((b << 6) + oc) << 14) + p] = acc[r];
    }
}

// ---------------------------------------------------------------------------
extern "C" void kernel_launch(void* const* d_in, const int* in_sizes, int n_in,
                              void* d_out, int out_size, void* d_ws, size_t ws_size,
                              hipStream_t stream) {
    (void)in_sizes; (void)n_in; (void)out_size; (void)ws_size;
    const float* img1  = (const float*)d_in[0];
    const float* img2  = (const float*)d_in[1];
    const float* img4  = (const float*)d_in[2];
    const float* img5  = (const float*)d_in[3];
    const float* osrc  = (const float*)d_in[4];
    const float* w_pc1 = (const float*)d_in[5];
    const float* b_pc1 = (const float*)d_in[6];
    const float* w_pc2 = (const float*)d_in[7];
    const float* b_pc2 = (const float*)d_in[8];
    const float* w_pc4 = (const float*)d_in[9];
    const float* b_pc4 = (const float*)d_in[10];
    const float* w_pc5 = (const float*)d_in[11];
    const float* b_pc5 = (const float*)d_in[12];
    const float* w_z   = (const float*)d_in[13];
    const float* b_z   = (const float*)d_in[14];
    const float* w_m   = (const float*)d_in[15];
    const float* b_m   = (const float*)d_in[16];
    const float* w_cv  = (const float*)d_in[17];
    float* out = (float*)d_out;

    float* wsf  = (float*)d_ws;
    float* offs = wsf;                    // 4 * 589824 floats
    float* zbuf = wsf + 4 * 589824;       // 294912
    float* mbuf = zbuf + 294912;          // 294912
    float* WcTr = mbuf + 294912;          // 36864 floats region (bf16 uses half)
    float* imgTr = WcTr + 36864;          // 8388608-float region

    __hip_bfloat16* WcPk  = (__hip_bfloat16*)WcTr;
    ushort*         imgTb = (ushort*)imgTr;   // bf16 imgT, 16.8 MB of region

    // Wpk/bpack/osT ALIAS the imgT region (conv pipeline finishes before
    // transpose_kernel overwrites imgT — same-stream serialization).
    __hip_bfloat16* Wpk   = (__hip_bfloat16*)imgTr;            // 153600 bf16
    float*          bpack = imgTr + 76800;                     // 96 f32
    __hip_bfloat16* osT   = (__hip_bfloat16*)(imgTr + 76912);  // 2230272 bf16

    packw_kernel<<<dim3((96 * 1600 + 255) / 256), 256, 0, stream>>>(
        w_pc1, b_pc1, w_pc2, b_pc2, w_pc4, b_pc4, w_pc5, b_pc5,
        w_z, b_z, w_m, b_m, Wpk, bpack);
    packosT_kernel<<<dim3(132, 2), 256, 0, stream>>>(osrc, osT);
    conv_mfma_kernel<<<dim3(128, 2, 3), 256, 0, stream>>>(
        Wpk, bpack, osT, offs, zbuf, mbuf);
    transpose_kernel<<<dim3(256, 2, 4), 256, 0, stream>>>(img1, img2, img4, img5, imgTb);
    wcpk_kernel<<<dim3(144), 256, 0, stream>>>(w_cv, WcPk);
    fused_kernel<<<dim3(2048), 256, 0, stream>>>(offs, zbuf, mbuf, imgTb, WcPk, out);
}

// Round 7
// 163.969 us; speedup vs baseline: 1.4165x; 1.4165x over previous
//
#include <hip/hip_runtime.h>
#include <hip/hip_bf16.h>
#include <math.h>

#define HWX 16384   // 128*128 pixels per (b, channel) plane

typedef __attribute__((ext_vector_type(8))) short short8v;
typedef __attribute__((ext_vector_type(4))) float f32x4;

__device__ inline ushort f2bf(float x) {
    union { __hip_bfloat16 h; ushort u; } cv;
    cv.h = __float2bfloat16(x);
    return cv.u;
}

// ---------------------------------------------------------------------------
// Pack six 5x5-conv weight sets -> Wpk[oc][k] bf16, k = (ky*5+kx)*64 + ic.
//   oc 0..17 pc1 | 18..35 pc2 | 36..53 pc4 | 54..71 pc5 | 72..80 z | 81..89 m
//   | 90..95 zero.  bias fp32 in bpack[96].  Source OIHW: o*1600 + ic*25 + kyx.
// ---------------------------------------------------------------------------
__global__ __launch_bounds__(256) void packw_kernel(
    const float* __restrict__ w1, const float* __restrict__ b1,
    const float* __restrict__ w2, const float* __restrict__ b2,
    const float* __restrict__ w4, const float* __restrict__ b4,
    const float* __restrict__ w5, const float* __restrict__ b5,
    const float* __restrict__ wz, const float* __restrict__ bz,
    const float* __restrict__ wm, const float* __restrict__ bm,
    __hip_bfloat16* __restrict__ Wpk, float* __restrict__ bpack)
{
    const int idx = blockIdx.x * 256 + threadIdx.x;
    if (idx < 96) {
        const int o = idx; float v = 0.f;
        if      (o < 18) v = b1[o];
        else if (o < 36) v = b2[o - 18];
        else if (o < 54) v = b4[o - 36];
        else if (o < 72) v = b5[o - 54];
        else if (o < 81) v = bz[o - 72];
        else if (o < 90) v = bm[o - 81];
        bpack[o] = v;
    }
    if (idx < 96 * 1600) {
        const int o   = idx / 1600;
        const int k   = idx - o * 1600;
        const int kyx = k >> 6;
        const int ic  = k & 63;
        const int off = ic * 25 + kyx;
        float v = 0.f;
        if      (o < 18) v = w1[o * 1600 + off];
        else if (o < 36) v = w2[(o - 18) * 1600 + off];
        else if (o < 54) v = w4[(o - 36) * 1600 + off];
        else if (o < 72) v = w5[(o - 54) * 1600 + off];
        else if (o < 81) v = wz[(o - 72) * 1600 + off];
        else if (o < 90) v = wm[(o - 81) * 1600 + off];
        Wpk[idx] = __float2bfloat16(v);
    }
}

// ---------------------------------------------------------------------------
// offset_source -> channel-last bf16 with baked-in zero pad ring:
//   osT[b][yy:132][xx:132][c:64]
// ---------------------------------------------------------------------------
__global__ __launch_bounds__(256) void packosT_kernel(
    const float* __restrict__ src, __hip_bfloat16* __restrict__ osT)
{
    const int yy = blockIdx.x;
    const int b  = blockIdx.y;
    __hip_bfloat16* dst = osT + ((size_t)b * 132 + yy) * 132 * 64;
    for (int idx = threadIdx.x; idx < 132 * 64; idx += 256) {
        const int xx = idx >> 6;
        const int c  = idx & 63;
        float v = 0.f;
        if (yy >= 2 && yy < 130 && xx >= 2 && xx < 130)
            v = src[(((b << 6) + c) << 14) + ((yy - 2) << 7) + (xx - 2)];
        dst[idx] = __float2bfloat16(v);
    }
}

// ---------------------------------------------------------------------------
// MFMA conv: C[96][16384] = Wpk[96][1600] x im2col(osT), per batch.
// Pure-register MFMA, no LDS/barriers. Block 256 = 4 waves (32 oc x 32 px
// each); grid (128 rows, 2 b, 3 ocg).
// ---------------------------------------------------------------------------
__global__ __launch_bounds__(256) void conv_mfma_kernel(
    const __hip_bfloat16* __restrict__ Wpk,   // [96][1600]
    const float* __restrict__ bpack,          // [96]
    const __hip_bfloat16* __restrict__ osT,   // [2][132][132][64]
    float* __restrict__ offs,                 // [4][2][18][HWX]
    float* __restrict__ zbuf,                 // [2][9][HWX]
    float* __restrict__ mbuf)                 // [2][9][HWX]
{
    const int y   = blockIdx.x;
    const int b   = blockIdx.y;
    const int ocg = blockIdx.z;
    const int t    = threadIdx.x;
    const int wv   = t >> 6;
    const int lane = t & 63;
    const int l15  = lane & 15;
    const int kgrp = lane >> 4;

    const ushort* W  = (const ushort*)Wpk;
    const ushort* ob = (const ushort*)osT + (size_t)b * (132 * 132 * 64);

    const int aoff0 = (ocg * 32 + l15) * 1600 + kgrp * 8;
    const int aoff1 = aoff0 + 16 * 1600;
    const int xloc0 = wv * 32 + l15;
    const int boff0 = (y * 132 + xloc0) * 64 + kgrp * 8;
    const int boff1 = boff0 + 16 * 64;

    f32x4 acc00 = {0.f,0.f,0.f,0.f}, acc01 = {0.f,0.f,0.f,0.f};
    f32x4 acc10 = {0.f,0.f,0.f,0.f}, acc11 = {0.f,0.f,0.f,0.f};

    #pragma unroll
    for (int ky = 0; ky < 5; ++ky)
    #pragma unroll
    for (int kx = 0; kx < 5; ++kx)
    #pragma unroll
    for (int ics = 0; ics < 2; ++ics) {
        const int uA = ((ky * 5 + kx) << 6) + (ics << 5);
        const int uB = ((ky * 132 + kx) << 6) + (ics << 5);
        const short8v a0 = *(const short8v*)(W  + aoff0 + uA);
        const short8v a1 = *(const short8v*)(W  + aoff1 + uA);
        const short8v b0 = *(const short8v*)(ob + boff0 + uB);
        const short8v b1 = *(const short8v*)(ob + boff1 + uB);
        acc00 = __builtin_amdgcn_mfma_f32_16x16x32_bf16(a0, b0, acc00, 0, 0, 0);
        acc01 = __builtin_amdgcn_mfma_f32_16x16x32_bf16(a0, b1, acc01, 0, 0, 0);
        acc10 = __builtin_amdgcn_mfma_f32_16x16x32_bf16(a1, b0, acc10, 0, 0, 0);
        acc11 = __builtin_amdgcn_mfma_f32_16x16x32_bf16(a1, b1, acc11, 0, 0, 0);
    }

    const int rowb = kgrp << 2;
    #pragma unroll
    for (int m = 0; m < 2; ++m)
    #pragma unroll
    for (int nf = 0; nf < 2; ++nf)
    #pragma unroll
    for (int r = 0; r < 4; ++r) {
        const f32x4 acc = (m == 0) ? (nf == 0 ? acc00 : acc01)
                                   : (nf == 0 ? acc10 : acc11);
        const int oc = ocg * 32 + m * 16 + rowb + r;
        if (oc < 90) {
            const int x = wv * 32 + nf * 16 + l15;
            const int p = (y << 7) + x;
            const float v = acc[r] + bpack[oc];
            if (oc < 72) {
                const int i = oc / 18, ch = oc - i * 18;
                offs[i * (2 * 18 * HWX) + (((b * 18) + ch) << 14) + p] = v;
            } else if (oc < 81) {
                zbuf[((b * 9 + (oc - 72)) << 14) + p] = 3.f / (1.f + expf(-v));
            } else {
                mbuf[((b * 9 + (oc - 81)) << 14) + p] = 1.f / (1.f + expf(-v));
            }
        }
    }
}

// ---------------------------------------------------------------------------
// Transpose img[b,c,y,x] fp32 -> imgT[img][b][p][c] bf16 (channel-last).
// ---------------------------------------------------------------------------
__global__ __launch_bounds__(256) void transpose_kernel(
    const float* __restrict__ i0, const float* __restrict__ i1,
    const float* __restrict__ i2, const float* __restrict__ i3,
    ushort* __restrict__ imgT)
{
    const int img = blockIdx.z;
    const int b   = blockIdx.y;
    const int p0  = blockIdx.x << 6;
    const float* src = (img == 0) ? i0 : (img == 1) ? i1 : (img == 2) ? i2 : i3;

    __shared__ float tile[64][65];
    const int t = threadIdx.x;
    const int pp = t & 63, c0 = t >> 6;
    #pragma unroll
    for (int k = 0; k < 16; ++k) {
        const int c = (k << 2) + c0;
        tile[c][pp] = src[(((b << 6) + c) << 14) + p0 + pp];
    }
    __syncthreads();
    const int c2 = t & 31, pl = t >> 5;
    #pragma unroll
    for (int k = 0; k < 8; ++k) {
        const int pi = (k << 3) + pl;
        const uint packed = (uint)f2bf(tile[2 * c2][pi])
                          | ((uint)f2bf(tile[2 * c2 + 1][pi]) << 16);
        *(uint*)(imgT + ((size_t)(((img << 1) + b) << 14) + p0 + pi) * 64 + 2 * c2)
            = packed;
    }
}

// ---------------------------------------------------------------------------
// WcPk = flat bf16 cast of w_conv[64][64][9]  (A-operand layout [oc][cn]).
// ---------------------------------------------------------------------------
__global__ __launch_bounds__(256) void wcpk_kernel(
    const float* __restrict__ wc, __hip_bfloat16* __restrict__ WcPk)
{
    const int idx = blockIdx.x * 256 + threadIdx.x;
    if (idx < 36864) WcPk[idx] = __float2bfloat16(wc[idx]);
}

// ---------------------------------------------------------------------------
// Fused deform-sample + weighted-sum + MFMA contraction.
// One block = 16 consecutive pixels of one row of one batch.
//   A: 576 units -> tap BYTE offsets + combined weights (LDS)
//   B: wide gather, lane=(px_sub 4, c4 16): 144 dwordx2 loads/wave via
//      wave-uniform base + 32-bit voffset; sched_barriers cap live loads
//   C: 4 waves x (16oc x 16px) MFMA, K=576: A=WcPk (global), B=s_sb (LDS)
// ---------------------------------------------------------------------------
__global__ __launch_bounds__(256, 4) void fused_kernel(
    const float* __restrict__ offs,   // [4][2][18][HWX]
    const float* __restrict__ zbuf,   // [2][9][HWX]
    const float* __restrict__ mbuf,   // [2][9][HWX]
    const ushort* __restrict__ imgT,  // [4][2][HWX][64] bf16
    const __hip_bfloat16* __restrict__ WcPk,  // [64][576]
    float* __restrict__ out)          // [2][64][HWX]
{
    __shared__ __hip_bfloat16 s_sb[16 * 584];   // 18688 B
    __shared__ int4   s_ti4[16 * 36];           // 9216 B  (byte offsets)
    __shared__ float4 s_tw4[16 * 36];           // 9216 B

    const int t   = threadIdx.x;
    const int pid = blockIdx.x;
    const int b   = pid >> 10;
    const int rem = pid & 1023;
    const int h   = rem >> 3;
    const int w0p = (rem & 7) << 4;

    // ---- phase A: taps (ti stored as byte offset = pixel*128) ----
    for (int u = t; u < 576; u += 256) {
        const int px   = u / 36;
        const int unit = u - px * 36;
        const int i    = unit / 9;
        const int n    = unit - i * 9;
        const int wcol = w0p + px;
        const int p    = (h << 7) + wcol;

        const float* ob = offs + i * (2 * 18 * HWX) + ((b * 18) << 14);
        const float ox = ob[(n << 14) + p];
        const float oy = ob[((n + 9) << 14) + p];
        const float z  = zbuf[((b * 9 + n) << 14) + p];
        const float mm = mbuf[((b * 9 + n) << 14) + p];

        const float zc0 = (i == 0) ? 1.f : 0.f;
        const float zc1 = (i == 0) ? (-11.f / 6.f) : (i == 1) ? 3.f
                         : (i == 2) ? -1.5f : (1.f / 3.f);
        const float zc2 = (i == 0) ? 1.f : (i == 1) ? -2.5f
                         : (i == 2) ? 2.f : -0.5f;
        const float zc3 = (i == 0) ? (-1.f / 6.f) : (i == 1) ? 0.5f
                         : (i == 2) ? -0.5f : (1.f / 6.f);
        const float zw   = zc0 + z * (zc1 + z * (zc2 + z * zc3));
        const float coef = zw * mm;

        const float pxf = (float)(h + n / 3) + ox;
        const float pyf = (float)(wcol + n % 3) + oy;
        const float flx = floorf(pxf), fly = floorf(pyf);
        const float qltx = fminf(fmaxf(flx, 0.f), 129.f);
        const float qrbx = fminf(fmaxf(flx + 1.f, 0.f), 129.f);
        const float qlty = fminf(fmaxf(fly, 0.f), 129.f);
        const float qrby = fminf(fmaxf(fly + 1.f, 0.f), 129.f);
        const float pxc = fminf(fmaxf(pxf, 0.f), 129.f);
        const float pyc = fminf(fmaxf(pyf, 0.f), 129.f);
        const float gxl = 1.f + (qltx - pxc);
        const float gxr = 1.f - (qrbx - pxc);
        const float gyl = 1.f + (qlty - pyc);
        const float gyr = 1.f - (qrby - pyc);
        const int ixl = (int)qltx, ixr = (int)qrbx;
        const int iyl = (int)qlty, iyr = (int)qrby;

        int4 ti; float4 tw;
        auto mk = [&](int qx, int qy, float g, int& ii, float& ww) {
            const bool valid = (qx >= 1) && (qx <= 128) && (qy >= 1) && (qy <= 128);
            ii = valid ? (((qx - 1) << 14) + ((qy - 1) << 7)) : 0;  // byte offset
            ww = valid ? g * coef : 0.f;
        };
        mk(ixl, iyl, gxl * gyl, ti.x, tw.x);
        mk(ixr, iyr, gxr * gyr, ti.y, tw.y);
        mk(ixr, iyl, gxr * gyl, ti.z, tw.z);
        mk(ixl, iyr, gxl * gyr, ti.w, tw.w);
        s_ti4[u] = ti;
        s_tw4[u] = tw;
    }
    __syncthreads();

    // ---- phase B: wide gather (uniform base + 32-bit voffset) ----
    const int lane = t & 63;
    const int wv   = t >> 6;
    const int c4   = lane & 15;
    const int pxs  = lane >> 4;
    const int px   = (wv << 2) + pxs;
    const int laneByte = c4 << 3;   // 4 channels * 2B

    f32x4 s4[9];
    #pragma unroll
    for (int n = 0; n < 9; ++n) s4[n] = (f32x4){0.f, 0.f, 0.f, 0.f};

    const int tb = px * 36;
    #pragma unroll 1
    for (int i = 0; i < 4; ++i) {
        // wave-uniform plane base: (i*2+b) * HWX*64 elements = <<20
        const char* ib = (const char*)(imgT + (((size_t)((i << 1) + b)) << 20));
        #pragma unroll
        for (int n = 0; n < 9; ++n) {
            const int4   tib = s_ti4[tb + i * 9 + n];
            const float4 tw  = s_tw4[tb + i * 9 + n];
            {
                const uint2 v = *(const uint2*)(ib + (tib.x + laneByte));
                s4[n].x = fmaf(tw.x, __uint_as_float(v.x << 16),         s4[n].x);
                s4[n].y = fmaf(tw.x, __uint_as_float(v.x & 0xffff0000u), s4[n].y);
                s4[n].z = fmaf(tw.x, __uint_as_float(v.y << 16),         s4[n].z);
                s4[n].w = fmaf(tw.x, __uint_as_float(v.y & 0xffff0000u), s4[n].w);
            }
            {
                const uint2 v = *(const uint2*)(ib + (tib.y + laneByte));
                s4[n].x = fmaf(tw.y, __uint_as_float(v.x << 16),         s4[n].x);
                s4[n].y = fmaf(tw.y, __uint_as_float(v.x & 0xffff0000u), s4[n].y);
                s4[n].z = fmaf(tw.y, __uint_as_float(v.y << 16),         s4[n].z);
                s4[n].w = fmaf(tw.y, __uint_as_float(v.y & 0xffff0000u), s4[n].w);
            }
            {
                const uint2 v = *(const uint2*)(ib + (tib.z + laneByte));
                s4[n].x = fmaf(tw.z, __uint_as_float(v.x << 16),         s4[n].x);
                s4[n].y = fmaf(tw.z, __uint_as_float(v.x & 0xffff0000u), s4[n].y);
                s4[n].z = fmaf(tw.z, __uint_as_float(v.y << 16),         s4[n].z);
                s4[n].w = fmaf(tw.z, __uint_as_float(v.y & 0xffff0000u), s4[n].w);
            }
            {
                const uint2 v = *(const uint2*)(ib + (tib.w + laneByte));
                s4[n].x = fmaf(tw.w, __uint_as_float(v.x << 16),         s4[n].x);
                s4[n].y = fmaf(tw.w, __uint_as_float(v.x & 0xffff0000u), s4[n].y);
                s4[n].z = fmaf(tw.w, __uint_as_float(v.y << 16),         s4[n].z);
                s4[n].w = fmaf(tw.w, __uint_as_float(v.y & 0xffff0000u), s4[n].w);
            }
            if (n == 2 || n == 5) __builtin_amdgcn_sched_barrier(0);
        }
        __builtin_amdgcn_sched_barrier(0);
    }

    // pack to bf16 pairs, write 9 contiguous uint2 (cn = (4*c4+j)*9 + n)
    uint bufu[18];
    #pragma unroll
    for (int k = 0; k < 18; ++k) {
        const int u0 = 2 * k, u1 = 2 * k + 1;
        const float v0 = s4[u0 % 9][u0 / 9];
        const float v1 = s4[u1 % 9][u1 / 9];
        bufu[k] = (uint)f2bf(v0) | ((uint)f2bf(v1) << 16);
    }
    {
        uint2* dst = (uint2*)((char*)s_sb + px * 1168 + c4 * 72);
        #pragma unroll
        for (int k = 0; k < 9; ++k)
            dst[k] = ((const uint2*)bufu)[k];
    }
    __syncthreads();

    // ---- phase C: MFMA contraction, wave wv -> oc block wv*16 ----
    const int l15  = lane & 15;
    const int kgrp = lane >> 4;
    const ushort* Wb = (const ushort*)WcPk + (wv * 16 + l15) * 576 + kgrp * 8;
    const ushort* sb = (const ushort*)s_sb + l15 * 584 + kgrp * 8;

    f32x4 acc = {0.f, 0.f, 0.f, 0.f};
    #pragma unroll
    for (int ks = 0; ks < 18; ++ks) {
        const short8v a  = *(const short8v*)(Wb + ks * 32);
        const short8v bb = *(const short8v*)(sb + ks * 32);
        acc = __builtin_amdgcn_mfma_f32_16x16x32_bf16(a, bb, acc, 0, 0, 0);
    }

    const int p = (h << 7) + w0p + l15;
    #pragma unroll
    for (int r = 0; r < 4; ++r) {
        const int oc = wv * 16 + (kgrp << 2) + r;
        out[(((b << 6) + oc) << 14) + p] = acc[r];
    }
}

// ---------------------------------------------------------------------------
extern "C" void kernel_launch(void* const* d_in, const int* in_sizes, int n_in,
                              void* d_out, int out_size, void* d_ws, size_t ws_size,
                              hipStream_t stream) {
    (void)in_sizes; (void)n_in; (void)out_size; (void)ws_size;
    const float* img1  = (const float*)d_in[0];
    const float* img2  = (const float*)d_in[1];
    const float* img4  = (const float*)d_in[2];
    const float* img5  = (const float*)d_in[3];
    const float* osrc  = (const float*)d_in[4];
    const float* w_pc1 = (const float*)d_in[5];
    const float* b_pc1 = (const float*)d_in[6];
    const float* w_pc2 = (const float*)d_in[7];
    const float* b_pc2 = (const float*)d_in[8];
    const float* w_pc4 = (const float*)d_in[9];
    const float* b_pc4 = (const float*)d_in[10];
    const float* w_pc5 = (const float*)d_in[11];
    const float* b_pc5 = (const float*)d_in[12];
    const float* w_z   = (const float*)d_in[13];
    const float* b_z   = (const float*)d_in[14];
    const float* w_m   = (const float*)d_in[15];
    const float* b_m   = (const float*)d_in[16];
    const float* w_cv  = (const float*)d_in[17];
    float* out = (float*)d_out;

    float* wsf  = (float*)d_ws;
    float* offs = wsf;                    // 4 * 589824 floats
    float* zbuf = wsf + 4 * 589824;       // 294912
    float* mbuf = zbuf + 294912;          // 294912
    float* WcTr = mbuf + 294912;          // 36864-float region (bf16 uses half)
    float* imgTr = WcTr + 36864;          // 8388608-float region

    __hip_bfloat16* WcPk  = (__hip_bfloat16*)WcTr;
    ushort*         imgTb = (ushort*)imgTr;   // bf16 imgT

    // Wpk/bpack/osT ALIAS the imgT region (conv pipeline finishes before
    // transpose_kernel overwrites imgT — same-stream serialization).
    __hip_bfloat16* Wpk   = (__hip_bfloat16*)imgTr;            // 153600 bf16
    float*          bpack = imgTr + 76800;                     // 96 f32
    __hip_bfloat16* osT   = (__hip_bfloat16*)(imgTr + 76912);  // 2230272 bf16

    packw_kernel<<<dim3((96 * 1600 + 255) / 256), 256, 0, stream>>>(
        w_pc1, b_pc1, w_pc2, b_pc2, w_pc4, b_pc4, w_pc5, b_pc5,
        w_z, b_z, w_m, b_m, Wpk, bpack);
    packosT_kernel<<<dim3(132, 2), 256, 0, stream>>>(osrc, osT);
    conv_mfma_kernel<<<dim3(128, 2, 3), 256, 0, stream>>>(
        Wpk, bpack, osT, offs, zbuf, mbuf);
    transpose_kernel<<<dim3(256, 2, 4), 256, 0, stream>>>(img1, img2, img4, img5, imgTb);
    wcpk_kernel<<<dim3(144), 256, 0, stream>>>(w_cv, WcPk);
    fused_kernel<<<dim3(2048), 256, 0, stream>>>(offs, zbuf, mbuf, imgTb, WcPk, out);
}

// Round 8
// 163.495 us; speedup vs baseline: 1.4206x; 1.0029x over previous
//
#include <hip/hip_runtime.h>
#include <hip/hip_bf16.h>
#include <math.h>

#define HWX 16384   // 128*128 pixels per (b, channel) plane

typedef __attribute__((ext_vector_type(8))) short short8v;
typedef __attribute__((ext_vector_type(4))) float f32x4;

__device__ inline ushort f2bf(float x) {
    union { __hip_bfloat16 h; ushort u; } cv;
    cv.h = __float2bfloat16(x);
    return cv.u;
}

// ---------------------------------------------------------------------------
// Pack six 5x5-conv weight sets -> Wpk[oc][k] bf16, k = (ky*5+kx)*64 + ic.
//   oc 0..17 pc1 | 18..35 pc2 | 36..53 pc4 | 54..71 pc5 | 72..80 z | 81..89 m
//   | 90..95 zero.  bias fp32 in bpack[96].  Source OIHW: o*1600 + ic*25 + kyx.
// ---------------------------------------------------------------------------
__global__ __launch_bounds__(256) void packw_kernel(
    const float* __restrict__ w1, const float* __restrict__ b1,
    const float* __restrict__ w2, const float* __restrict__ b2,
    const float* __restrict__ w4, const float* __restrict__ b4,
    const float* __restrict__ w5, const float* __restrict__ b5,
    const float* __restrict__ wz, const float* __restrict__ bz,
    const float* __restrict__ wm, const float* __restrict__ bm,
    __hip_bfloat16* __restrict__ Wpk, float* __restrict__ bpack)
{
    const int idx = blockIdx.x * 256 + threadIdx.x;
    if (idx < 96) {
        const int o = idx; float v = 0.f;
        if      (o < 18) v = b1[o];
        else if (o < 36) v = b2[o - 18];
        else if (o < 54) v = b4[o - 36];
        else if (o < 72) v = b5[o - 54];
        else if (o < 81) v = bz[o - 72];
        else if (o < 90) v = bm[o - 81];
        bpack[o] = v;
    }
    if (idx < 96 * 1600) {
        const int o   = idx / 1600;
        const int k   = idx - o * 1600;
        const int kyx = k >> 6;
        const int ic  = k & 63;
        const int off = ic * 25 + kyx;
        float v = 0.f;
        if      (o < 18) v = w1[o * 1600 + off];
        else if (o < 36) v = w2[(o - 18) * 1600 + off];
        else if (o < 54) v = w4[(o - 36) * 1600 + off];
        else if (o < 72) v = w5[(o - 54) * 1600 + off];
        else if (o < 81) v = wz[(o - 72) * 1600 + off];
        else if (o < 90) v = wm[(o - 81) * 1600 + off];
        Wpk[idx] = __float2bfloat16(v);
    }
}

// ---------------------------------------------------------------------------
// offset_source -> channel-last bf16 with baked-in zero pad ring:
//   osT[b][yy:132][xx:132][c:64]
// ---------------------------------------------------------------------------
__global__ __launch_bounds__(256) void packosT_kernel(
    const float* __restrict__ src, __hip_bfloat16* __restrict__ osT)
{
    const int yy = blockIdx.x;
    const int b  = blockIdx.y;
    __hip_bfloat16* dst = osT + ((size_t)b * 132 + yy) * 132 * 64;
    for (int idx = threadIdx.x; idx < 132 * 64; idx += 256) {
        const int xx = idx >> 6;
        const int c  = idx & 63;
        float v = 0.f;
        if (yy >= 2 && yy < 130 && xx >= 2 && xx < 130)
            v = src[(((b << 6) + c) << 14) + ((yy - 2) << 7) + (xx - 2)];
        dst[idx] = __float2bfloat16(v);
    }
}

// ---------------------------------------------------------------------------
// MFMA conv: C[96][16384] = Wpk[96][1600] x im2col(osT), per batch.
// Pure-register MFMA with EXPLICIT DEPTH-4 LOAD PIPELINE (r7: compiler
// serialized load->mfma at VGPR=32; queue forces ~16 loads in flight).
// Block 256 = 4 waves (32 oc x 32 px each); grid (128 rows, 2 b, 3 ocg).
// ---------------------------------------------------------------------------
__global__ __launch_bounds__(256) void conv_mfma_kernel(
    const __hip_bfloat16* __restrict__ Wpk,   // [96][1600]
    const float* __restrict__ bpack,          // [96]
    const __hip_bfloat16* __restrict__ osT,   // [2][132][132][64]
    float* __restrict__ offs,                 // [4][2][18][HWX]
    float* __restrict__ zbuf,                 // [2][9][HWX]
    float* __restrict__ mbuf)                 // [2][9][HWX]
{
    const int y   = blockIdx.x;
    const int b   = blockIdx.y;
    const int ocg = blockIdx.z;
    const int t    = threadIdx.x;
    const int wv   = t >> 6;
    const int lane = t & 63;
    const int l15  = lane & 15;
    const int kgrp = lane >> 4;

    const ushort* W  = (const ushort*)Wpk;
    const ushort* ob = (const ushort*)osT + (size_t)b * (132 * 132 * 64);

    const int aoff0 = (ocg * 32 + l15) * 1600 + kgrp * 8;
    const int aoff1 = aoff0 + 16 * 1600;
    const int xloc0 = wv * 32 + l15;
    const int boff0 = (y * 132 + xloc0) * 64 + kgrp * 8;
    const int boff1 = boff0 + 16 * 64;

    f32x4 acc00 = {0.f,0.f,0.f,0.f}, acc01 = {0.f,0.f,0.f,0.f};
    f32x4 acc10 = {0.f,0.f,0.f,0.f}, acc11 = {0.f,0.f,0.f,0.f};

    // rolling 4-deep fragment queue (indices static after full unroll)
    short8v qa0[4], qa1[4], qb0[4], qb1[4];

#define LOADSTEP(s, slot) {                                        \
        const int kyx_ = (s) >> 1, ics_ = (s) & 1;                 \
        const int uA_ = (kyx_ << 6) + (ics_ << 5);                 \
        const int ky_ = kyx_ / 5, kx_ = kyx_ % 5;                  \
        const int uB_ = ((ky_ * 132 + kx_) << 6) + (ics_ << 5);    \
        qa0[slot] = *(const short8v*)(W  + aoff0 + uA_);           \
        qa1[slot] = *(const short8v*)(W  + aoff1 + uA_);           \
        qb0[slot] = *(const short8v*)(ob + boff0 + uB_);           \
        qb1[slot] = *(const short8v*)(ob + boff1 + uB_); }

    LOADSTEP(0, 0)
    LOADSTEP(1, 1)
    LOADSTEP(2, 2)

    #pragma unroll
    for (int ks = 0; ks < 50; ++ks) {
        if (ks + 3 < 50) LOADSTEP(ks + 3, (ks + 3) & 3)
        const int cur = ks & 3;
        acc00 = __builtin_amdgcn_mfma_f32_16x16x32_bf16(qa0[cur], qb0[cur], acc00, 0, 0, 0);
        acc01 = __builtin_amdgcn_mfma_f32_16x16x32_bf16(qa0[cur], qb1[cur], acc01, 0, 0, 0);
        acc10 = __builtin_amdgcn_mfma_f32_16x16x32_bf16(qa1[cur], qb0[cur], acc10, 0, 0, 0);
        acc11 = __builtin_amdgcn_mfma_f32_16x16x32_bf16(qa1[cur], qb1[cur], acc11, 0, 0, 0);
    }
#undef LOADSTEP

    const int rowb = kgrp << 2;
    #pragma unroll
    for (int m = 0; m < 2; ++m)
    #pragma unroll
    for (int nf = 0; nf < 2; ++nf)
    #pragma unroll
    for (int r = 0; r < 4; ++r) {
        const f32x4 acc = (m == 0) ? (nf == 0 ? acc00 : acc01)
                                   : (nf == 0 ? acc10 : acc11);
        const int oc = ocg * 32 + m * 16 + rowb + r;
        if (oc < 90) {
            const int x = wv * 32 + nf * 16 + l15;
            const int p = (y << 7) + x;
            const float v = acc[r] + bpack[oc];
            if (oc < 72) {
                const int i = oc / 18, ch = oc - i * 18;
                offs[i * (2 * 18 * HWX) + (((b * 18) + ch) << 14) + p] = v;
            } else if (oc < 81) {
                zbuf[((b * 9 + (oc - 72)) << 14) + p] = 3.f / (1.f + expf(-v));
            } else {
                mbuf[((b * 9 + (oc - 81)) << 14) + p] = 1.f / (1.f + expf(-v));
            }
        }
    }
}

// ---------------------------------------------------------------------------
// Transpose img[b,c,y,x] fp32 -> imgT[img][b][p][c] bf16 (channel-last).
// ---------------------------------------------------------------------------
__global__ __launch_bounds__(256) void transpose_kernel(
    const float* __restrict__ i0, const float* __restrict__ i1,
    const float* __restrict__ i2, const float* __restrict__ i3,
    ushort* __restrict__ imgT)
{
    const int img = blockIdx.z;
    const int b   = blockIdx.y;
    const int p0  = blockIdx.x << 6;
    const float* src = (img == 0) ? i0 : (img == 1) ? i1 : (img == 2) ? i2 : i3;

    __shared__ float tile[64][65];
    const int t = threadIdx.x;
    const int pp = t & 63, c0 = t >> 6;
    #pragma unroll
    for (int k = 0; k < 16; ++k) {
        const int c = (k << 2) + c0;
        tile[c][pp] = src[(((b << 6) + c) << 14) + p0 + pp];
    }
    __syncthreads();
    const int c2 = t & 31, pl = t >> 5;
    #pragma unroll
    for (int k = 0; k < 8; ++k) {
        const int pi = (k << 3) + pl;
        const uint packed = (uint)f2bf(tile[2 * c2][pi])
                          | ((uint)f2bf(tile[2 * c2 + 1][pi]) << 16);
        *(uint*)(imgT + ((size_t)(((img << 1) + b) << 14) + p0 + pi) * 64 + 2 * c2)
            = packed;
    }
}

// ---------------------------------------------------------------------------
// WcPk = flat bf16 cast of w_conv[64][64][9]  (A-operand layout [oc][cn]).
// ---------------------------------------------------------------------------
__global__ __launch_bounds__(256) void wcpk_kernel(
    const float* __restrict__ wc, __hip_bfloat16* __restrict__ WcPk)
{
    const int idx = blockIdx.x * 256 + threadIdx.x;
    if (idx < 36864) WcPk[idx] = __float2bfloat16(wc[idx]);
}

// ---------------------------------------------------------------------------
// Fused deform-sample + weighted-sum + MFMA contraction.
// One block = 16 consecutive pixels of one row of one batch.
// ---------------------------------------------------------------------------
__global__ __launch_bounds__(256, 4) void fused_kernel(
    const float* __restrict__ offs,   // [4][2][18][HWX]
    const float* __restrict__ zbuf,   // [2][9][HWX]
    const float* __restrict__ mbuf,   // [2][9][HWX]
    const ushort* __restrict__ imgT,  // [4][2][HWX][64] bf16
    const __hip_bfloat16* __restrict__ WcPk,  // [64][576]
    float* __restrict__ out)          // [2][64][HWX]
{
    __shared__ __hip_bfloat16 s_sb[16 * 584];   // 18688 B
    __shared__ int4   s_ti4[16 * 36];           // 9216 B  (byte offsets)
    __shared__ float4 s_tw4[16 * 36];           // 9216 B

    const int t   = threadIdx.x;
    const int pid = blockIdx.x;
    const int b   = pid >> 10;
    const int rem = pid & 1023;
    const int h   = rem >> 3;
    const int w0p = (rem & 7) << 4;

    // ---- phase A: taps (ti stored as byte offset = pixel*128) ----
    for (int u = t; u < 576; u += 256) {
        const int px   = u / 36;
        const int unit = u - px * 36;
        const int i    = unit / 9;
        const int n    = unit - i * 9;
        const int wcol = w0p + px;
        const int p    = (h << 7) + wcol;

        const float* ob = offs + i * (2 * 18 * HWX) + ((b * 18) << 14);
        const float ox = ob[(n << 14) + p];
        const float oy = ob[((n + 9) << 14) + p];
        const float z  = zbuf[((b * 9 + n) << 14) + p];
        const float mm = mbuf[((b * 9 + n) << 14) + p];

        const float zc0 = (i == 0) ? 1.f : 0.f;
        const float zc1 = (i == 0) ? (-11.f / 6.f) : (i == 1) ? 3.f
                         : (i == 2) ? -1.5f : (1.f / 3.f);
        const float zc2 = (i == 0) ? 1.f : (i == 1) ? -2.5f
                         : (i == 2) ? 2.f : -0.5f;
        const float zc3 = (i == 0) ? (-1.f / 6.f) : (i == 1) ? 0.5f
                         : (i == 2) ? -0.5f : (1.f / 6.f);
        const float zw   = zc0 + z * (zc1 + z * (zc2 + z * zc3));
        const float coef = zw * mm;

        const float pxf = (float)(h + n / 3) + ox;
        const float pyf = (float)(wcol + n % 3) + oy;
        const float flx = floorf(pxf), fly = floorf(pyf);
        const float qltx = fminf(fmaxf(flx, 0.f), 129.f);
        const float qrbx = fminf(fmaxf(flx + 1.f, 0.f), 129.f);
        const float qlty = fminf(fmaxf(fly, 0.f), 129.f);
        const float qrby = fminf(fmaxf(fly + 1.f, 0.f), 129.f);
        const float pxc = fminf(fmaxf(pxf, 0.f), 129.f);
        const float pyc = fminf(fmaxf(pyf, 0.f), 129.f);
        const float gxl = 1.f + (qltx - pxc);
        const float gxr = 1.f - (qrbx - pxc);
        const float gyl = 1.f + (qlty - pyc);
        const float gyr = 1.f - (qrby - pyc);
        const int ixl = (int)qltx, ixr = (int)qrbx;
        const int iyl = (int)qlty, iyr = (int)qrby;

        int4 ti; float4 tw;
        auto mk = [&](int qx, int qy, float g, int& ii, float& ww) {
            const bool valid = (qx >= 1) && (qx <= 128) && (qy >= 1) && (qy <= 128);
            ii = valid ? (((qx - 1) << 14) + ((qy - 1) << 7)) : 0;  // byte offset
            ww = valid ? g * coef : 0.f;
        };
        mk(ixl, iyl, gxl * gyl, ti.x, tw.x);
        mk(ixr, iyr, gxr * gyr, ti.y, tw.y);
        mk(ixr, iyl, gxr * gyl, ti.z, tw.z);
        mk(ixl, iyr, gxl * gyr, ti.w, tw.w);
        s_ti4[u] = ti;
        s_tw4[u] = tw;
    }
    __syncthreads();

    // ---- phase B: wide gather (uniform base + 32-bit voffset) ----
    const int lane = t & 63;
    const int wv   = t >> 6;
    const int c4   = lane & 15;
    const int pxs  = lane >> 4;
    const int px   = (wv << 2) + pxs;
    const int laneByte = c4 << 3;   // 4 channels * 2B

    f32x4 s4[9];
    #pragma unroll
    for (int n = 0; n < 9; ++n) s4[n] = (f32x4){0.f, 0.f, 0.f, 0.f};

    const int tb = px * 36;
    #pragma unroll 1
    for (int i = 0; i < 4; ++i) {
        const char* ib = (const char*)(imgT + (((size_t)((i << 1) + b)) << 20));
        #pragma unroll
        for (int n = 0; n < 9; ++n) {
            const int4   tib = s_ti4[tb + i * 9 + n];
            const float4 tw  = s_tw4[tb + i * 9 + n];
            {
                const uint2 v = *(const uint2*)(ib + (tib.x + laneByte));
                s4[n].x = fmaf(tw.x, __uint_as_float(v.x << 16),         s4[n].x);
                s4[n].y = fmaf(tw.x, __uint_as_float(v.x & 0xffff0000u), s4[n].y);
                s4[n].z = fmaf(tw.x, __uint_as_float(v.y << 16),         s4[n].z);
                s4[n].w = fmaf(tw.x, __uint_as_float(v.y & 0xffff0000u), s4[n].w);
            }
            {
                const uint2 v = *(const uint2*)(ib + (tib.y + laneByte));
                s4[n].x = fmaf(tw.y, __uint_as_float(v.x << 16),         s4[n].x);
                s4[n].y = fmaf(tw.y, __uint_as_float(v.x & 0xffff0000u), s4[n].y);
                s4[n].z = fmaf(tw.y, __uint_as_float(v.y << 16),         s4[n].z);
                s4[n].w = fmaf(tw.y, __uint_as_float(v.y & 0xffff0000u), s4[n].w);
            }
            {
                const uint2 v = *(const uint2*)(ib + (tib.z + laneByte));
                s4[n].x = fmaf(tw.z, __uint_as_float(v.x << 16),         s4[n].x);
                s4[n].y = fmaf(tw.z, __uint_as_float(v.x & 0xffff0000u), s4[n].y);
                s4[n].z = fmaf(tw.z, __uint_as_float(v.y << 16),         s4[n].z);
                s4[n].w = fmaf(tw.z, __uint_as_float(v.y & 0xffff0000u), s4[n].w);
            }
            {
                const uint2 v = *(const uint2*)(ib + (tib.w + laneByte));
                s4[n].x = fmaf(tw.w, __uint_as_float(v.x << 16),         s4[n].x);
                s4[n].y = fmaf(tw.w, __uint_as_float(v.x & 0xffff0000u), s4[n].y);
                s4[n].z = fmaf(tw.w, __uint_as_float(v.y << 16),         s4[n].z);
                s4[n].w = fmaf(tw.w, __uint_as_float(v.y & 0xffff0000u), s4[n].w);
            }
            if (n == 2 || n == 5) __builtin_amdgcn_sched_barrier(0);
        }
        __builtin_amdgcn_sched_barrier(0);
    }

    // pack to bf16 pairs, write 9 contiguous uint2 (cn = (4*c4+j)*9 + n)
    uint bufu[18];
    #pragma unroll
    for (int k = 0; k < 18; ++k) {
        const int u0 = 2 * k, u1 = 2 * k + 1;
        const float v0 = s4[u0 % 9][u0 / 9];
        const float v1 = s4[u1 % 9][u1 / 9];
        bufu[k] = (uint)f2bf(v0) | ((uint)f2bf(v1) << 16);
    }
    {
        uint2* dst = (uint2*)((char*)s_sb + px * 1168 + c4 * 72);
        #pragma unroll
        for (int k = 0; k < 9; ++k)
            dst[k] = ((const uint2*)bufu)[k];
    }
    __syncthreads();

    // ---- phase C: MFMA contraction, wave wv -> oc block wv*16 ----
    const int l15  = lane & 15;
    const int kgrp = lane >> 4;
    const ushort* Wb = (const ushort*)WcPk + (wv * 16 + l15) * 576 + kgrp * 8;
    const ushort* sb = (const ushort*)s_sb + l15 * 584 + kgrp * 8;

    f32x4 acc = {0.f, 0.f, 0.f, 0.f};
    #pragma unroll
    for (int ks = 0; ks < 18; ++ks) {
        const short8v a  = *(const short8v*)(Wb + ks * 32);
        const short8v bb = *(const short8v*)(sb + ks * 32);
        acc = __builtin_amdgcn_mfma_f32_16x16x32_bf16(a, bb, acc, 0, 0, 0);
    }

    const int p = (h << 7) + w0p + l15;
    #pragma unroll
    for (int r = 0; r < 4; ++r) {
        const int oc = wv * 16 + (kgrp << 2) + r;
        out[(((b << 6) + oc) << 14) + p] = acc[r];
    }
}

// ---------------------------------------------------------------------------
extern "C" void kernel_launch(void* const* d_in, const int* in_sizes, int n_in,
                              void* d_out, int out_size, void* d_ws, size_t ws_size,
                              hipStream_t stream) {
    (void)in_sizes; (void)n_in; (void)out_size; (void)ws_size;
    const float* img1  = (const float*)d_in[0];
    const float* img2  = (const float*)d_in[1];
    const float* img4  = (const float*)d_in[2];
    const float* img5  = (const float*)d_in[3];
    const float* osrc  = (const float*)d_in[4];
    const float* w_pc1 = (const float*)d_in[5];
    const float* b_pc1 = (const float*)d_in[6];
    const float* w_pc2 = (const float*)d_in[7];
    const float* b_pc2 = (const float*)d_in[8];
    const float* w_pc4 = (const float*)d_in[9];
    const float* b_pc4 = (const float*)d_in[10];
    const float* w_pc5 = (const float*)d_in[11];
    const float* b_pc5 = (const float*)d_in[12];
    const float* w_z   = (const float*)d_in[13];
    const float* b_z   = (const float*)d_in[14];
    const float* w_m   = (const float*)d_in[15];
    const float* b_m   = (const float*)d_in[16];
    const float* w_cv  = (const float*)d_in[17];
    float* out = (float*)d_out;

    float* wsf  = (float*)d_ws;
    float* offs = wsf;                    // 4 * 589824 floats
    float* zbuf = wsf + 4 * 589824;       // 294912
    float* mbuf = zbuf + 294912;          // 294912
    float* WcTr = mbuf + 294912;          // 36864-float region (bf16 uses half)
    float* imgTr = WcTr + 36864;          // 8388608-float region

    __hip_bfloat16* WcPk  = (__hip_bfloat16*)WcTr;
    ushort*         imgTb = (ushort*)imgTr;   // bf16 imgT

    // Wpk/bpack/osT ALIAS the imgT region (conv pipeline finishes before
    // transpose_kernel overwrites imgT — same-stream serialization).
    __hip_bfloat16* Wpk   = (__hip_bfloat16*)imgTr;            // 153600 bf16
    float*          bpack = imgTr + 76800;                     // 96 f32
    __hip_bfloat16* osT   = (__hip_bfloat16*)(imgTr + 76912);  // 2230272 bf16

    packw_kernel<<<dim3((96 * 1600 + 255) / 256), 256, 0, stream>>>(
        w_pc1, b_pc1, w_pc2, b_pc2, w_pc4, b_pc4, w_pc5, b_pc5,
        w_z, b_z, w_m, b_m, Wpk, bpack);
    packosT_kernel<<<dim3(132, 2), 256, 0, stream>>>(osrc, osT);
    conv_mfma_kernel<<<dim3(128, 2, 3), 256, 0, stream>>>(
        Wpk, bpack, osT, offs, zbuf, mbuf);
    transpose_kernel<<<dim3(256, 2, 4), 256, 0, stream>>>(img1, img2, img4, img5, imgTb);
    wcpk_kernel<<<dim3(144), 256, 0, stream>>>(w_cv, WcPk);
    fused_kernel<<<dim3(2048), 256, 0, stream>>>(offs, zbuf, mbuf, imgTb, WcPk, out);
}

// Round 9
// 163.331 us; speedup vs baseline: 1.4220x; 1.0010x over previous
//
#include <hip/hip_runtime.h>
#include <hip/hip_bf16.h>
#include <math.h>

#define HWX 16384   // 128*128 pixels per (b, channel) plane

typedef __attribute__((ext_vector_type(8))) short short8v;
typedef __attribute__((ext_vector_type(4))) float f32x4;

__device__ inline ushort f2bf(float x) {
    union { __hip_bfloat16 h; ushort u; } cv;
    cv.h = __float2bfloat16(x);
    return cv.u;
}

// ---------------------------------------------------------------------------
// Pack six 5x5-conv weight sets -> Wpk[oc][k] bf16, k = (ky*5+kx)*64 + ic.
//   oc 0..17 pc1 | 18..35 pc2 | 36..53 pc4 | 54..71 pc5 | 72..80 z | 81..89 m
//   | 90..95 zero.  bias fp32 in bpack[96].  Source OIHW: o*1600 + ic*25 + kyx.
// ---------------------------------------------------------------------------
__global__ __launch_bounds__(256) void packw_kernel(
    const float* __restrict__ w1, const float* __restrict__ b1,
    const float* __restrict__ w2, const float* __restrict__ b2,
    const float* __restrict__ w4, const float* __restrict__ b4,
    const float* __restrict__ w5, const float* __restrict__ b5,
    const float* __restrict__ wz, const float* __restrict__ bz,
    const float* __restrict__ wm, const float* __restrict__ bm,
    __hip_bfloat16* __restrict__ Wpk, float* __restrict__ bpack)
{
    const int idx = blockIdx.x * 256 + threadIdx.x;
    if (idx < 96) {
        const int o = idx; float v = 0.f;
        if      (o < 18) v = b1[o];
        else if (o < 36) v = b2[o - 18];
        else if (o < 54) v = b4[o - 36];
        else if (o < 72) v = b5[o - 54];
        else if (o < 81) v = bz[o - 72];
        else if (o < 90) v = bm[o - 81];
        bpack[o] = v;
    }
    if (idx < 96 * 1600) {
        const int o   = idx / 1600;
        const int k   = idx - o * 1600;
        const int kyx = k >> 6;
        const int ic  = k & 63;
        const int off = ic * 25 + kyx;
        float v = 0.f;
        if      (o < 18) v = w1[o * 1600 + off];
        else if (o < 36) v = w2[(o - 18) * 1600 + off];
        else if (o < 54) v = w4[(o - 36) * 1600 + off];
        else if (o < 72) v = w5[(o - 54) * 1600 + off];
        else if (o < 81) v = wz[(o - 72) * 1600 + off];
        else if (o < 90) v = wm[(o - 81) * 1600 + off];
        Wpk[idx] = __float2bfloat16(v);
    }
}

// ---------------------------------------------------------------------------
// offset_source -> channel-last bf16 with baked-in zero pad ring:
//   osT[b][yy:132][xx:132][c:64]
// ---------------------------------------------------------------------------
__global__ __launch_bounds__(256) void packosT_kernel(
    const float* __restrict__ src, __hip_bfloat16* __restrict__ osT)
{
    const int yy = blockIdx.x;
    const int b  = blockIdx.y;
    __hip_bfloat16* dst = osT + ((size_t)b * 132 + yy) * 132 * 64;
    for (int idx = threadIdx.x; idx < 132 * 64; idx += 256) {
        const int xx = idx >> 6;
        const int c  = idx & 63;
        float v = 0.f;
        if (yy >= 2 && yy < 130 && xx >= 2 && xx < 130)
            v = src[(((b << 6) + c) << 14) + ((yy - 2) << 7) + (xx - 2)];
        dst[idx] = __float2bfloat16(v);
    }
}

// ---------------------------------------------------------------------------
// MFMA conv: C[96][16384] = Wpk[96][1600] x im2col(osT), per batch.
// Pure-register MFMA with depth-4 load pipeline.
// __launch_bounds__(256, 3): r8 showed that with 0 LDS and no min-wave hint,
// the backend targets 8 waves/SIMD -> 32 VGPRs -> fully serialized loads
// (MfmaUtil 5%). Grid is only 3 blocks/CU, so declare 3 waves/EU to raise
// the VGPR budget (~168) and let the scheduler keep the queue in flight.
// ---------------------------------------------------------------------------
__global__ __launch_bounds__(256, 3) void conv_mfma_kernel(
    const __hip_bfloat16* __restrict__ Wpk,   // [96][1600]
    const float* __restrict__ bpack,          // [96]
    const __hip_bfloat16* __restrict__ osT,   // [2][132][132][64]
    float* __restrict__ offs,                 // [4][2][18][HWX]
    float* __restrict__ zbuf,                 // [2][9][HWX]
    float* __restrict__ mbuf)                 // [2][9][HWX]
{
    const int y   = blockIdx.x;
    const int b   = blockIdx.y;
    const int ocg = blockIdx.z;
    const int t    = threadIdx.x;
    const int wv   = t >> 6;
    const int lane = t & 63;
    const int l15  = lane & 15;
    const int kgrp = lane >> 4;

    const ushort* W  = (const ushort*)Wpk;
    const ushort* ob = (const ushort*)osT + (size_t)b * (132 * 132 * 64);

    const int aoff0 = (ocg * 32 + l15) * 1600 + kgrp * 8;
    const int aoff1 = aoff0 + 16 * 1600;
    const int xloc0 = wv * 32 + l15;
    const int boff0 = (y * 132 + xloc0) * 64 + kgrp * 8;
    const int boff1 = boff0 + 16 * 64;

    f32x4 acc00 = {0.f,0.f,0.f,0.f}, acc01 = {0.f,0.f,0.f,0.f};
    f32x4 acc10 = {0.f,0.f,0.f,0.f}, acc11 = {0.f,0.f,0.f,0.f};

    // rolling 4-deep fragment queue (indices static after full unroll)
    short8v qa0[4], qa1[4], qb0[4], qb1[4];

#define LOADSTEP(s, slot) {                                        \
        const int kyx_ = (s) >> 1, ics_ = (s) & 1;                 \
        const int uA_ = (kyx_ << 6) + (ics_ << 5);                 \
        const int ky_ = kyx_ / 5, kx_ = kyx_ % 5;                  \
        const int uB_ = ((ky_ * 132 + kx_) << 6) + (ics_ << 5);    \
        qa0[slot] = *(const short8v*)(W  + aoff0 + uA_);           \
        qa1[slot] = *(const short8v*)(W  + aoff1 + uA_);           \
        qb0[slot] = *(const short8v*)(ob + boff0 + uB_);           \
        qb1[slot] = *(const short8v*)(ob + boff1 + uB_); }

    LOADSTEP(0, 0)
    LOADSTEP(1, 1)
    LOADSTEP(2, 2)

    #pragma unroll
    for (int ks = 0; ks < 50; ++ks) {
        if (ks + 3 < 50) LOADSTEP(ks + 3, (ks + 3) & 3)
        const int cur = ks & 3;
        acc00 = __builtin_amdgcn_mfma_f32_16x16x32_bf16(qa0[cur], qb0[cur], acc00, 0, 0, 0);
        acc01 = __builtin_amdgcn_mfma_f32_16x16x32_bf16(qa0[cur], qb1[cur], acc01, 0, 0, 0);
        acc10 = __builtin_amdgcn_mfma_f32_16x16x32_bf16(qa1[cur], qb0[cur], acc10, 0, 0, 0);
        acc11 = __builtin_amdgcn_mfma_f32_16x16x32_bf16(qa1[cur], qb1[cur], acc11, 0, 0, 0);
    }
#undef LOADSTEP

    const int rowb = kgrp << 2;
    #pragma unroll
    for (int m = 0; m < 2; ++m)
    #pragma unroll
    for (int nf = 0; nf < 2; ++nf)
    #pragma unroll
    for (int r = 0; r < 4; ++r) {
        const f32x4 acc = (m == 0) ? (nf == 0 ? acc00 : acc01)
                                   : (nf == 0 ? acc10 : acc11);
        const int oc = ocg * 32 + m * 16 + rowb + r;
        if (oc < 90) {
            const int x = wv * 32 + nf * 16 + l15;
            const int p = (y << 7) + x;
            const float v = acc[r] + bpack[oc];
            if (oc < 72) {
                const int i = oc / 18, ch = oc - i * 18;
                offs[i * (2 * 18 * HWX) + (((b * 18) + ch) << 14) + p] = v;
            } else if (oc < 81) {
                zbuf[((b * 9 + (oc - 72)) << 14) + p] = 3.f / (1.f + expf(-v));
            } else {
                mbuf[((b * 9 + (oc - 81)) << 14) + p] = 1.f / (1.f + expf(-v));
            }
        }
    }
}

// ---------------------------------------------------------------------------
// Transpose img[b,c,y,x] fp32 -> imgT[img][b][p][c] bf16 (channel-last).
// ---------------------------------------------------------------------------
__global__ __launch_bounds__(256) void transpose_kernel(
    const float* __restrict__ i0, const float* __restrict__ i1,
    const float* __restrict__ i2, const float* __restrict__ i3,
    ushort* __restrict__ imgT)
{
    const int img = blockIdx.z;
    const int b   = blockIdx.y;
    const int p0  = blockIdx.x << 6;
    const float* src = (img == 0) ? i0 : (img == 1) ? i1 : (img == 2) ? i2 : i3;

    __shared__ float tile[64][65];
    const int t = threadIdx.x;
    const int pp = t & 63, c0 = t >> 6;
    #pragma unroll
    for (int k = 0; k < 16; ++k) {
        const int c = (k << 2) + c0;
        tile[c][pp] = src[(((b << 6) + c) << 14) + p0 + pp];
    }
    __syncthreads();
    const int c2 = t & 31, pl = t >> 5;
    #pragma unroll
    for (int k = 0; k < 8; ++k) {
        const int pi = (k << 3) + pl;
        const uint packed = (uint)f2bf(tile[2 * c2][pi])
                          | ((uint)f2bf(tile[2 * c2 + 1][pi]) << 16);
        *(uint*)(imgT + ((size_t)(((img << 1) + b) << 14) + p0 + pi) * 64 + 2 * c2)
            = packed;
    }
}

// ---------------------------------------------------------------------------
// WcPk = flat bf16 cast of w_conv[64][64][9]  (A-operand layout [oc][cn]).
// ---------------------------------------------------------------------------
__global__ __launch_bounds__(256) void wcpk_kernel(
    const float* __restrict__ wc, __hip_bfloat16* __restrict__ WcPk)
{
    const int idx = blockIdx.x * 256 + threadIdx.x;
    if (idx < 36864) WcPk[idx] = __float2bfloat16(wc[idx]);
}

// ---------------------------------------------------------------------------
// Fused deform-sample + weighted-sum + MFMA contraction.
// One block = 16 consecutive pixels of one row of one batch.
// ---------------------------------------------------------------------------
__global__ __launch_bounds__(256, 4) void fused_kernel(
    const float* __restrict__ offs,   // [4][2][18][HWX]
    const float* __restrict__ zbuf,   // [2][9][HWX]
    const float* __restrict__ mbuf,   // [2][9][HWX]
    const ushort* __restrict__ imgT,  // [4][2][HWX][64] bf16
    const __hip_bfloat16* __restrict__ WcPk,  // [64][576]
    float* __restrict__ out)          // [2][64][HWX]
{
    __shared__ __hip_bfloat16 s_sb[16 * 584];   // 18688 B
    __shared__ int4   s_ti4[16 * 36];           // 9216 B  (byte offsets)
    __shared__ float4 s_tw4[16 * 36];           // 9216 B

    const int t   = threadIdx.x;
    const int pid = blockIdx.x;
    const int b   = pid >> 10;
    const int rem = pid & 1023;
    const int h   = rem >> 3;
    const int w0p = (rem & 7) << 4;

    // ---- phase A: taps (ti stored as byte offset = pixel*128) ----
    for (int u = t; u < 576; u += 256) {
        const int px   = u / 36;
        const int unit = u - px * 36;
        const int i    = unit / 9;
        const int n    = unit - i * 9;
        const int wcol = w0p + px;
        const int p    = (h << 7) + wcol;

        const float* ob = offs + i * (2 * 18 * HWX) + ((b * 18) << 14);
        const float ox = ob[(n << 14) + p];
        const float oy = ob[((n + 9) << 14) + p];
        const float z  = zbuf[((b * 9 + n) << 14) + p];
        const float mm = mbuf[((b * 9 + n) << 14) + p];

        const float zc0 = (i == 0) ? 1.f : 0.f;
        const float zc1 = (i == 0) ? (-11.f / 6.f) : (i == 1) ? 3.f
                         : (i == 2) ? -1.5f : (1.f / 3.f);
        const float zc2 = (i == 0) ? 1.f : (i == 1) ? -2.5f
                         : (i == 2) ? 2.f : -0.5f;
        const float zc3 = (i == 0) ? (-1.f / 6.f) : (i == 1) ? 0.5f
                         : (i == 2) ? -0.5f : (1.f / 6.f);
        const float zw   = zc0 + z * (zc1 + z * (zc2 + z * zc3));
        const float coef = zw * mm;

        const float pxf = (float)(h + n / 3) + ox;
        const float pyf = (float)(wcol + n % 3) + oy;
        const float flx = floorf(pxf), fly = floorf(pyf);
        const float qltx = fminf(fmaxf(flx, 0.f), 129.f);
        const float qrbx = fminf(fmaxf(flx + 1.f, 0.f), 129.f);
        const float qlty = fminf(fmaxf(fly, 0.f), 129.f);
        const float qrby = fminf(fmaxf(fly + 1.f, 0.f), 129.f);
        const float pxc = fminf(fmaxf(pxf, 0.f), 129.f);
        const float pyc = fminf(fmaxf(pyf, 0.f), 129.f);
        const float gxl = 1.f + (qltx - pxc);
        const float gxr = 1.f - (qrbx - pxc);
        const float gyl = 1.f + (qlty - pyc);
        const float gyr = 1.f - (qrby - pyc);
        const int ixl = (int)qltx, ixr = (int)qrbx;
        const int iyl = (int)qlty, iyr = (int)qrby;

        int4 ti; float4 tw;
        auto mk = [&](int qx, int qy, float g, int& ii, float& ww) {
            const bool valid = (qx >= 1) && (qx <= 128) && (qy >= 1) && (qy <= 128);
            ii = valid ? (((qx - 1) << 14) + ((qy - 1) << 7)) : 0;  // byte offset
            ww = valid ? g * coef : 0.f;
        };
        mk(ixl, iyl, gxl * gyl, ti.x, tw.x);
        mk(ixr, iyr, gxr * gyr, ti.y, tw.y);
        mk(ixr, iyl, gxr * gyl, ti.z, tw.z);
        mk(ixl, iyr, gxl * gyr, ti.w, tw.w);
        s_ti4[u] = ti;
        s_tw4[u] = tw;
    }
    __syncthreads();

    // ---- phase B: wide gather (uniform base + 32-bit voffset) ----
    const int lane = t & 63;
    const int wv   = t >> 6;
    const int c4   = lane & 15;
    const int pxs  = lane >> 4;
    const int px   = (wv << 2) + pxs;
    const int laneByte = c4 << 3;   // 4 channels * 2B

    f32x4 s4[9];
    #pragma unroll
    for (int n = 0; n < 9; ++n) s4[n] = (f32x4){0.f, 0.f, 0.f, 0.f};

    const int tb = px * 36;
    #pragma unroll 1
    for (int i = 0; i < 4; ++i) {
        const char* ib = (const char*)(imgT + (((size_t)((i << 1) + b)) << 20));
        #pragma unroll
        for (int n = 0; n < 9; ++n) {
            const int4   tib = s_ti4[tb + i * 9 + n];
            const float4 tw  = s_tw4[tb + i * 9 + n];
            {
                const uint2 v = *(const uint2*)(ib + (tib.x + laneByte));
                s4[n].x = fmaf(tw.x, __uint_as_float(v.x << 16),         s4[n].x);
                s4[n].y = fmaf(tw.x, __uint_as_float(v.x & 0xffff0000u), s4[n].y);
                s4[n].z = fmaf(tw.x, __uint_as_float(v.y << 16),         s4[n].z);
                s4[n].w = fmaf(tw.x, __uint_as_float(v.y & 0xffff0000u), s4[n].w);
            }
            {
                const uint2 v = *(const uint2*)(ib + (tib.y + laneByte));
                s4[n].x = fmaf(tw.y, __uint_as_float(v.x << 16),         s4[n].x);
                s4[n].y = fmaf(tw.y, __uint_as_float(v.x & 0xffff0000u), s4[n].y);
                s4[n].z = fmaf(tw.y, __uint_as_float(v.y << 16),         s4[n].z);
                s4[n].w = fmaf(tw.y, __uint_as_float(v.y & 0xffff0000u), s4[n].w);
            }
            {
                const uint2 v = *(const uint2*)(ib + (tib.z + laneByte));
                s4[n].x = fmaf(tw.z, __uint_as_float(v.x << 16),         s4[n].x);
                s4[n].y = fmaf(tw.z, __uint_as_float(v.x & 0xffff0000u), s4[n].y);
                s4[n].z = fmaf(tw.z, __uint_as_float(v.y << 16),         s4[n].z);
                s4[n].w = fmaf(tw.z, __uint_as_float(v.y & 0xffff0000u), s4[n].w);
            }
            {
                const uint2 v = *(const uint2*)(ib + (tib.w + laneByte));
                s4[n].x = fmaf(tw.w, __uint_as_float(v.x << 16),         s4[n].x);
                s4[n].y = fmaf(tw.w, __uint_as_float(v.x & 0xffff0000u), s4[n].y);
                s4[n].z = fmaf(tw.w, __uint_as_float(v.y << 16),         s4[n].z);
                s4[n].w = fmaf(tw.w, __uint_as_float(v.y & 0xffff0000u), s4[n].w);
            }
            if (n == 2 || n == 5) __builtin_amdgcn_sched_barrier(0);
        }
        __builtin_amdgcn_sched_barrier(0);
    }

    // pack to bf16 pairs, write 9 contiguous uint2 (cn = (4*c4+j)*9 + n)
    uint bufu[18];
    #pragma unroll
    for (int k = 0; k < 18; ++k) {
        const int u0 = 2 * k, u1 = 2 * k + 1;
        const float v0 = s4[u0 % 9][u0 / 9];
        const float v1 = s4[u1 % 9][u1 / 9];
        bufu[k] = (uint)f2bf(v0) | ((uint)f2bf(v1) << 16);
    }
    {
        uint2* dst = (uint2*)((char*)s_sb + px * 1168 + c4 * 72);
        #pragma unroll
        for (int k = 0; k < 9; ++k)
            dst[k] = ((const uint2*)bufu)[k];
    }
    __syncthreads();

    // ---- phase C: MFMA contraction, wave wv -> oc block wv*16 ----
    const int l15  = lane & 15;
    const int kgrp = lane >> 4;
    const ushort* Wb = (const ushort*)WcPk + (wv * 16 + l15) * 576 + kgrp * 8;
    const ushort* sb = (const ushort*)s_sb + l15 * 584 + kgrp * 8;

    f32x4 acc = {0.f, 0.f, 0.f, 0.f};
    #pragma unroll
    for (int ks = 0; ks < 18; ++ks) {
        const short8v a  = *(const short8v*)(Wb + ks * 32);
        const short8v bb = *(const short8v*)(sb + ks * 32);
        acc = __builtin_amdgcn_mfma_f32_16x16x32_bf16(a, bb, acc, 0, 0, 0);
    }

    const int p = (h << 7) + w0p + l15;
    #pragma unroll
    for (int r = 0; r < 4; ++r) {
        const int oc = wv * 16 + (kgrp << 2) + r;
        out[(((b << 6) + oc) << 14) + p] = acc[r];
    }
}

// ---------------------------------------------------------------------------
extern "C" void kernel_launch(void* const* d_in, const int* in_sizes, int n_in,
                              void* d_out, int out_size, void* d_ws, size_t ws_size,
                              hipStream_t stream) {
    (void)in_sizes; (void)n_in; (void)out_size; (void)ws_size;
    const float* img1  = (const float*)d_in[0];
    const float* img2  = (const float*)d_in[1];
    const float* img4  = (const float*)d_in[2];
    const float* img5  = (const float*)d_in[3];
    const float* osrc  = (const float*)d_in[4];
    const float* w_pc1 = (const float*)d_in[5];
    const float* b_pc1 = (const float*)d_in[6];
    const float* w_pc2 = (const float*)d_in[7];
    const float* b_pc2 = (const float*)d_in[8];
    const float* w_pc4 = (const float*)d_in[9];
    const float* b_pc4 = (const float*)d_in[10];
    const float* w_pc5 = (const float*)d_in[11];
    const float* b_pc5 = (const float*)d_in[12];
    const float* w_z   = (const float*)d_in[13];
    const float* b_z   = (const float*)d_in[14];
    const float* w_m   = (const float*)d_in[15];
    const float* b_m   = (const float*)d_in[16];
    const float* w_cv  = (const float*)d_in[17];
    float* out = (float*)d_out;

    float* wsf  = (float*)d_ws;
    float* offs = wsf;                    // 4 * 589824 floats
    float* zbuf = wsf + 4 * 589824;       // 294912
    float* mbuf = zbuf + 294912;          // 294912
    float* WcTr = mbuf + 294912;          // 36864-float region (bf16 uses half)
    float* imgTr = WcTr + 36864;          // 8388608-float region

    __hip_bfloat16* WcPk  = (__hip_bfloat16*)WcTr;
    ushort*         imgTb = (ushort*)imgTr;   // bf16 imgT

    // Wpk/bpack/osT ALIAS the imgT region (conv pipeline finishes before
    // transpose_kernel overwrites imgT — same-stream serialization).
    __hip_bfloat16* Wpk   = (__hip_bfloat16*)imgTr;            // 153600 bf16
    float*          bpack = imgTr + 76800;                     // 96 f32
    __hip_bfloat16* osT   = (__hip_bfloat16*)(imgTr + 76912);  // 2230272 bf16

    packw_kernel<<<dim3((96 * 1600 + 255) / 256), 256, 0, stream>>>(
        w_pc1, b_pc1, w_pc2, b_pc2, w_pc4, b_pc4, w_pc5, b_pc5,
        w_z, b_z, w_m, b_m, Wpk, bpack);
    packosT_kernel<<<dim3(132, 2), 256, 0, stream>>>(osrc, osT);
    conv_mfma_kernel<<<dim3(128, 2, 3), 256, 0, stream>>>(
        Wpk, bpack, osT, offs, zbuf, mbuf);
    transpose_kernel<<<dim3(256, 2, 4), 256, 0, stream>>>(img1, img2, img4, img5, imgTb);
    wcpk_kernel<<<dim3(144), 256, 0, stream>>>(w_cv, WcPk);
    fused_kernel<<<dim3(2048), 256, 0, stream>>>(offs, zbuf, mbuf, imgTb, WcPk, out);
}

// Round 10
// 162.808 us; speedup vs baseline: 1.4266x; 1.0032x over previous
//
#include <hip/hip_runtime.h>
#include <hip/hip_bf16.h>
#include <math.h>

#define HWX 16384   // 128*128 pixels per (b, channel) plane

typedef __attribute__((ext_vector_type(8))) short short8v;
typedef __attribute__((ext_vector_type(4))) float f32x4;

__device__ inline ushort f2bf(float x) {
    union { __hip_bfloat16 h; ushort u; } cv;
    cv.h = __float2bfloat16(x);
    return cv.u;
}

// ---------------------------------------------------------------------------
// Pack six 5x5-conv weight sets -> Wpk[oc][k] bf16, k = (ky*5+kx)*64 + ic.
//   oc 0..17 pc1 | 18..35 pc2 | 36..53 pc4 | 54..71 pc5 | 72..80 z | 81..89 m
//   | 90..95 zero.  bias fp32 in bpack[96].  Source OIHW: o*1600 + ic*25 + kyx.
// ---------------------------------------------------------------------------
__global__ __launch_bounds__(256) void packw_kernel(
    const float* __restrict__ w1, const float* __restrict__ b1,
    const float* __restrict__ w2, const float* __restrict__ b2,
    const float* __restrict__ w4, const float* __restrict__ b4,
    const float* __restrict__ w5, const float* __restrict__ b5,
    const float* __restrict__ wz, const float* __restrict__ bz,
    const float* __restrict__ wm, const float* __restrict__ bm,
    __hip_bfloat16* __restrict__ Wpk, float* __restrict__ bpack)
{
    const int idx = blockIdx.x * 256 + threadIdx.x;
    if (idx < 96) {
        const int o = idx; float v = 0.f;
        if      (o < 18) v = b1[o];
        else if (o < 36) v = b2[o - 18];
        else if (o < 54) v = b4[o - 36];
        else if (o < 72) v = b5[o - 54];
        else if (o < 81) v = bz[o - 72];
        else if (o < 90) v = bm[o - 81];
        bpack[o] = v;
    }
    if (idx < 96 * 1600) {
        const int o   = idx / 1600;
        const int k   = idx - o * 1600;
        const int kyx = k >> 6;
        const int ic  = k & 63;
        const int off = ic * 25 + kyx;
        float v = 0.f;
        if      (o < 18) v = w1[o * 1600 + off];
        else if (o < 36) v = w2[(o - 18) * 1600 + off];
        else if (o < 54) v = w4[(o - 36) * 1600 + off];
        else if (o < 72) v = w5[(o - 54) * 1600 + off];
        else if (o < 81) v = wz[(o - 72) * 1600 + off];
        else if (o < 90) v = wm[(o - 81) * 1600 + off];
        Wpk[idx] = __float2bfloat16(v);
    }
}

// ---------------------------------------------------------------------------
// offset_source -> channel-last bf16 with baked-in zero pad ring:
//   osT[b][yy:132][xx:132][c:64]
// ---------------------------------------------------------------------------
__global__ __launch_bounds__(256) void packosT_kernel(
    const float* __restrict__ src, __hip_bfloat16* __restrict__ osT)
{
    const int yy = blockIdx.x;
    const int b  = blockIdx.y;
    __hip_bfloat16* dst = osT + ((size_t)b * 132 + yy) * 132 * 64;
    for (int idx = threadIdx.x; idx < 132 * 64; idx += 256) {
        const int xx = idx >> 6;
        const int c  = idx & 63;
        float v = 0.f;
        if (yy >= 2 && yy < 130 && xx >= 2 && xx < 130)
            v = src[(((b << 6) + c) << 14) + ((yy - 2) << 7) + (xx - 2)];
        dst[idx] = __float2bfloat16(v);
    }
}

// ---------------------------------------------------------------------------
// MFMA conv: C[96][16384] = Wpk[96][1600] x im2col(osT), per batch.
// r8/r9: compiler sank all loads next to MFMAs (VGPR=32, MfmaUtil 5%) —
// source-level queue + launch_bounds hints are both ignored. This round:
// sched_group_barrier DIRECTIVES pin the emission order (T19):
//   [12-load prologue][4 loads (step k+3) | 4 MFMAs (step k)] x 47 [4 MFMAs] x 3
// forcing ~12 loads in flight per wave (AITER vmcnt(12) pattern).
// ---------------------------------------------------------------------------
#define SGB __builtin_amdgcn_sched_group_barrier
__global__ __launch_bounds__(256, 3) void conv_mfma_kernel(
    const __hip_bfloat16* __restrict__ Wpk,   // [96][1600]
    const float* __restrict__ bpack,          // [96]
    const __hip_bfloat16* __restrict__ osT,   // [2][132][132][64]
    float* __restrict__ offs,                 // [4][2][18][HWX]
    float* __restrict__ zbuf,                 // [2][9][HWX]
    float* __restrict__ mbuf)                 // [2][9][HWX]
{
    const int y   = blockIdx.x;
    const int b   = blockIdx.y;
    const int ocg = blockIdx.z;
    const int t    = threadIdx.x;
    const int wv   = t >> 6;
    const int lane = t & 63;
    const int l15  = lane & 15;
    const int kgrp = lane >> 4;

    const ushort* W  = (const ushort*)Wpk;
    const ushort* ob = (const ushort*)osT + (size_t)b * (132 * 132 * 64);

    const int aoff0 = (ocg * 32 + l15) * 1600 + kgrp * 8;
    const int aoff1 = aoff0 + 16 * 1600;
    const int xloc0 = wv * 32 + l15;
    const int boff0 = (y * 132 + xloc0) * 64 + kgrp * 8;
    const int boff1 = boff0 + 16 * 64;

    f32x4 acc00 = {0.f,0.f,0.f,0.f}, acc01 = {0.f,0.f,0.f,0.f};
    f32x4 acc10 = {0.f,0.f,0.f,0.f}, acc11 = {0.f,0.f,0.f,0.f};

    // rolling 4-deep fragment queue (indices static after full unroll)
    short8v qa0[4], qa1[4], qb0[4], qb1[4];

#define LOADSTEP(s, slot) {                                        \
        const int kyx_ = (s) >> 1, ics_ = (s) & 1;                 \
        const int uA_ = (kyx_ << 6) + (ics_ << 5);                 \
        const int ky_ = kyx_ / 5, kx_ = kyx_ % 5;                  \
        const int uB_ = ((ky_ * 132 + kx_) << 6) + (ics_ << 5);    \
        qa0[slot] = *(const short8v*)(W  + aoff0 + uA_);           \
        qa1[slot] = *(const short8v*)(W  + aoff1 + uA_);           \
        qb0[slot] = *(const short8v*)(ob + boff0 + uB_);           \
        qb1[slot] = *(const short8v*)(ob + boff1 + uB_); }

    LOADSTEP(0, 0)
    LOADSTEP(1, 1)
    LOADSTEP(2, 2)
    SGB(0x20, 12, 0);   // pin 12 prologue VMEM reads at region start

    #pragma unroll
    for (int ks = 0; ks < 50; ++ks) {
        if (ks + 3 < 50) {
            LOADSTEP(ks + 3, (ks + 3) & 3)
            SGB(0x20, 4, 0);   // 4 loads of step ks+3 ...
        }
        const int cur = ks & 3;
        acc00 = __builtin_amdgcn_mfma_f32_16x16x32_bf16(qa0[cur], qb0[cur], acc00, 0, 0, 0);
        acc01 = __builtin_amdgcn_mfma_f32_16x16x32_bf16(qa0[cur], qb1[cur], acc01, 0, 0, 0);
        acc10 = __builtin_amdgcn_mfma_f32_16x16x32_bf16(qa1[cur], qb0[cur], acc10, 0, 0, 0);
        acc11 = __builtin_amdgcn_mfma_f32_16x16x32_bf16(qa1[cur], qb1[cur], acc11, 0, 0, 0);
        SGB(0x8, 4, 0);        // ... then 4 MFMAs of step ks
    }
#undef LOADSTEP

    const int rowb = kgrp << 2;
    #pragma unroll
    for (int m = 0; m < 2; ++m)
    #pragma unroll
    for (int nf = 0; nf < 2; ++nf)
    #pragma unroll
    for (int r = 0; r < 4; ++r) {
        const f32x4 acc = (m == 0) ? (nf == 0 ? acc00 : acc01)
                                   : (nf == 0 ? acc10 : acc11);
        const int oc = ocg * 32 + m * 16 + rowb + r;
        if (oc < 90) {
            const int x = wv * 32 + nf * 16 + l15;
            const int p = (y << 7) + x;
            const float v = acc[r] + bpack[oc];
            if (oc < 72) {
                const int i = oc / 18, ch = oc - i * 18;
                offs[i * (2 * 18 * HWX) + (((b * 18) + ch) << 14) + p] = v;
            } else if (oc < 81) {
                zbuf[((b * 9 + (oc - 72)) << 14) + p] = 3.f / (1.f + expf(-v));
            } else {
                mbuf[((b * 9 + (oc - 81)) << 14) + p] = 1.f / (1.f + expf(-v));
            }
        }
    }
}
#undef SGB

// ---------------------------------------------------------------------------
// Transpose img[b,c,y,x] fp32 -> imgT[img][b][p][c] bf16 (channel-last).
// ---------------------------------------------------------------------------
__global__ __launch_bounds__(256) void transpose_kernel(
    const float* __restrict__ i0, const float* __restrict__ i1,
    const float* __restrict__ i2, const float* __restrict__ i3,
    ushort* __restrict__ imgT)
{
    const int img = blockIdx.z;
    const int b   = blockIdx.y;
    const int p0  = blockIdx.x << 6;
    const float* src = (img == 0) ? i0 : (img == 1) ? i1 : (img == 2) ? i2 : i3;

    __shared__ float tile[64][65];
    const int t = threadIdx.x;
    const int pp = t & 63, c0 = t >> 6;
    #pragma unroll
    for (int k = 0; k < 16; ++k) {
        const int c = (k << 2) + c0;
        tile[c][pp] = src[(((b << 6) + c) << 14) + p0 + pp];
    }
    __syncthreads();
    const int c2 = t & 31, pl = t >> 5;
    #pragma unroll
    for (int k = 0; k < 8; ++k) {
        const int pi = (k << 3) + pl;
        const uint packed = (uint)f2bf(tile[2 * c2][pi])
                          | ((uint)f2bf(tile[2 * c2 + 1][pi]) << 16);
        *(uint*)(imgT + ((size_t)(((img << 1) + b) << 14) + p0 + pi) * 64 + 2 * c2)
            = packed;
    }
}

// ---------------------------------------------------------------------------
// WcPk = flat bf16 cast of w_conv[64][64][9]  (A-operand layout [oc][cn]).
// ---------------------------------------------------------------------------
__global__ __launch_bounds__(256) void wcpk_kernel(
    const float* __restrict__ wc, __hip_bfloat16* __restrict__ WcPk)
{
    const int idx = blockIdx.x * 256 + threadIdx.x;
    if (idx < 36864) WcPk[idx] = __float2bfloat16(wc[idx]);
}

// ---------------------------------------------------------------------------
// Fused deform-sample + weighted-sum + MFMA contraction.
// One block = 16 consecutive pixels of one row of one batch.
// ---------------------------------------------------------------------------
__global__ __launch_bounds__(256, 4) void fused_kernel(
    const float* __restrict__ offs,   // [4][2][18][HWX]
    const float* __restrict__ zbuf,   // [2][9][HWX]
    const float* __restrict__ mbuf,   // [2][9][HWX]
    const ushort* __restrict__ imgT,  // [4][2][HWX][64] bf16
    const __hip_bfloat16* __restrict__ WcPk,  // [64][576]
    float* __restrict__ out)          // [2][64][HWX]
{
    __shared__ __hip_bfloat16 s_sb[16 * 584];   // 18688 B
    __shared__ int4   s_ti4[16 * 36];           // 9216 B  (byte offsets)
    __shared__ float4 s_tw4[16 * 36];           // 9216 B

    const int t   = threadIdx.x;
    const int pid = blockIdx.x;
    const int b   = pid >> 10;
    const int rem = pid & 1023;
    const int h   = rem >> 3;
    const int w0p = (rem & 7) << 4;

    // ---- phase A: taps (ti stored as byte offset = pixel*128) ----
    for (int u = t; u < 576; u += 256) {
        const int px   = u / 36;
        const int unit = u - px * 36;
        const int i    = unit / 9;
        const int n    = unit - i * 9;
        const int wcol = w0p + px;
        const int p    = (h << 7) + wcol;

        const float* ob = offs + i * (2 * 18 * HWX) + ((b * 18) << 14);
        const float ox = ob[(n << 14) + p];
        const float oy = ob[((n + 9) << 14) + p];
        const float z  = zbuf[((b * 9 + n) << 14) + p];
        const float mm = mbuf[((b * 9 + n) << 14) + p];

        const float zc0 = (i == 0) ? 1.f : 0.f;
        const float zc1 = (i == 0) ? (-11.f / 6.f) : (i == 1) ? 3.f
                         : (i == 2) ? -1.5f : (1.f / 3.f);
        const float zc2 = (i == 0) ? 1.f : (i == 1) ? -2.5f
                         : (i == 2) ? 2.f : -0.5f;
        const float zc3 = (i == 0) ? (-1.f / 6.f) : (i == 1) ? 0.5f
                         : (i == 2) ? -0.5f : (1.f / 6.f);
        const float zw   = zc0 + z * (zc1 + z * (zc2 + z * zc3));
        const float coef = zw * mm;

        const float pxf = (float)(h + n / 3) + ox;
        const float pyf = (float)(wcol + n % 3) + oy;
        const float flx = floorf(pxf), fly = floorf(pyf);
        const float qltx = fminf(fmaxf(flx, 0.f), 129.f);
        const float qrbx = fminf(fmaxf(flx + 1.f, 0.f), 129.f);
        const float qlty = fminf(fmaxf(fly, 0.f), 129.f);
        const float qrby = fminf(fmaxf(fly + 1.f, 0.f), 129.f);
        const float pxc = fminf(fmaxf(pxf, 0.f), 129.f);
        const float pyc = fminf(fmaxf(pyf, 0.f), 129.f);
        const float gxl = 1.f + (qltx - pxc);
        const float gxr = 1.f - (qrbx - pxc);
        const float gyl = 1.f + (qlty - pyc);
        const float gyr = 1.f - (qrby - pyc);
        const int ixl = (int)qltx, ixr = (int)qrbx;
        const int iyl = (int)qlty, iyr = (int)qrby;

        int4 ti; float4 tw;
        auto mk = [&](int qx, int qy, float g, int& ii, float& ww) {
            const bool valid = (qx >= 1) && (qx <= 128) && (qy >= 1) && (qy <= 128);
            ii = valid ? (((qx - 1) << 14) + ((qy - 1) << 7)) : 0;  // byte offset
            ww = valid ? g * coef : 0.f;
        };
        mk(ixl, iyl, gxl * gyl, ti.x, tw.x);
        mk(ixr, iyr, gxr * gyr, ti.y, tw.y);
        mk(ixr, iyl, gxr * gyl, ti.z, tw.z);
        mk(ixl, iyr, gxl * gyr, ti.w, tw.w);
        s_ti4[u] = ti;
        s_tw4[u] = tw;
    }
    __syncthreads();

    // ---- phase B: wide gather (uniform base + 32-bit voffset) ----
    const int lane = t & 63;
    const int wv   = t >> 6;
    const int c4   = lane & 15;
    const int pxs  = lane >> 4;
    const int px   = (wv << 2) + pxs;
    const int laneByte = c4 << 3;   // 4 channels * 2B

    f32x4 s4[9];
    #pragma unroll
    for (int n = 0; n < 9; ++n) s4[n] = (f32x4){0.f, 0.f, 0.f, 0.f};

    const int tb = px * 36;
    #pragma unroll 1
    for (int i = 0; i < 4; ++i) {
        const char* ib = (const char*)(imgT + (((size_t)((i << 1) + b)) << 20));
        #pragma unroll
        for (int n = 0; n < 9; ++n) {
            const int4   tib = s_ti4[tb + i * 9 + n];
            const float4 tw  = s_tw4[tb + i * 9 + n];
            {
                const uint2 v = *(const uint2*)(ib + (tib.x + laneByte));
                s4[n].x = fmaf(tw.x, __uint_as_float(v.x << 16),         s4[n].x);
                s4[n].y = fmaf(tw.x, __uint_as_float(v.x & 0xffff0000u), s4[n].y);
                s4[n].z = fmaf(tw.x, __uint_as_float(v.y << 16),         s4[n].z);
                s4[n].w = fmaf(tw.x, __uint_as_float(v.y & 0xffff0000u), s4[n].w);
            }
            {
                const uint2 v = *(const uint2*)(ib + (tib.y + laneByte));
                s4[n].x = fmaf(tw.y, __uint_as_float(v.x << 16),         s4[n].x);
                s4[n].y = fmaf(tw.y, __uint_as_float(v.x & 0xffff0000u), s4[n].y);
                s4[n].z = fmaf(tw.y, __uint_as_float(v.y << 16),         s4[n].z);
                s4[n].w = fmaf(tw.y, __uint_as_float(v.y & 0xffff0000u), s4[n].w);
            }
            {
                const uint2 v = *(const uint2*)(ib + (tib.z + laneByte));
                s4[n].x = fmaf(tw.z, __uint_as_float(v.x << 16),         s4[n].x);
                s4[n].y = fmaf(tw.z, __uint_as_float(v.x & 0xffff0000u), s4[n].y);
                s4[n].z = fmaf(tw.z, __uint_as_float(v.y << 16),         s4[n].z);
                s4[n].w = fmaf(tw.z, __uint_as_float(v.y & 0xffff0000u), s4[n].w);
            }
            {
                const uint2 v = *(const uint2*)(ib + (tib.w + laneByte));
                s4[n].x = fmaf(tw.w, __uint_as_float(v.x << 16),         s4[n].x);
                s4[n].y = fmaf(tw.w, __uint_as_float(v.x & 0xffff0000u), s4[n].y);
                s4[n].z = fmaf(tw.w, __uint_as_float(v.y << 16),         s4[n].z);
                s4[n].w = fmaf(tw.w, __uint_as_float(v.y & 0xffff0000u), s4[n].w);
            }
            if (n == 2 || n == 5) __builtin_amdgcn_sched_barrier(0);
        }
        __builtin_amdgcn_sched_barrier(0);
    }

    // pack to bf16 pairs, write 9 contiguous uint2 (cn = (4*c4+j)*9 + n)
    uint bufu[18];
    #pragma unroll
    for (int k = 0; k < 18; ++k) {
        const int u0 = 2 * k, u1 = 2 * k + 1;
        const float v0 = s4[u0 % 9][u0 / 9];
        const float v1 = s4[u1 % 9][u1 / 9];
        bufu[k] = (uint)f2bf(v0) | ((uint)f2bf(v1) << 16);
    }
    {
        uint2* dst = (uint2*)((char*)s_sb + px * 1168 + c4 * 72);
        #pragma unroll
        for (int k = 0; k < 9; ++k)
            dst[k] = ((const uint2*)bufu)[k];
    }
    __syncthreads();

    // ---- phase C: MFMA contraction, wave wv -> oc block wv*16 ----
    const int l15  = lane & 15;
    const int kgrp = lane >> 4;
    const ushort* Wb = (const ushort*)WcPk + (wv * 16 + l15) * 576 + kgrp * 8;
    const ushort* sb = (const ushort*)s_sb + l15 * 584 + kgrp * 8;

    f32x4 acc = {0.f, 0.f, 0.f, 0.f};
    #pragma unroll
    for (int ks = 0; ks < 18; ++ks) {
        const short8v a  = *(const short8v*)(Wb + ks * 32);
        const short8v bb = *(const short8v*)(sb + ks * 32);
        acc = __builtin_amdgcn_mfma_f32_16x16x32_bf16(a, bb, acc, 0, 0, 0);
    }

    const int p = (h << 7) + w0p + l15;
    #pragma unroll
    for (int r = 0; r < 4; ++r) {
        const int oc = wv * 16 + (kgrp << 2) + r;
        out[(((b << 6) + oc) << 14) + p] = acc[r];
    }
}

// ---------------------------------------------------------------------------
extern "C" void kernel_launch(void* const* d_in, const int* in_sizes, int n_in,
                              void* d_out, int out_size, void* d_ws, size_t ws_size,
                              hipStream_t stream) {
    (void)in_sizes; (void)n_in; (void)out_size; (void)ws_size;
    const float* img1  = (const float*)d_in[0];
    const float* img2  = (const float*)d_in[1];
    const float* img4  = (const float*)d_in[2];
    const float* img5  = (const float*)d_in[3];
    const float* osrc  = (const float*)d_in[4];
    const float* w_pc1 = (const float*)d_in[5];
    const float* b_pc1 = (const float*)d_in[6];
    const float* w_pc2 = (const float*)d_in[7];
    const float* b_pc2 = (const float*)d_in[8];
    const float* w_pc4 = (const float*)d_in[9];
    const float* b_pc4 = (const float*)d_in[10];
    const float* w_pc5 = (const float*)d_in[11];
    const float* b_pc5 = (const float*)d_in[12];
    const float* w_z   = (const float*)d_in[13];
    const float* b_z   = (const float*)d_in[14];
    const float* w_m   = (const float*)d_in[15];
    const float* b_m   = (const float*)d_in[16];
    const float* w_cv  = (const float*)d_in[17];
    float* out = (float*)d_out;

    float* wsf  = (float*)d_ws;
    float* offs = wsf;                    // 4 * 589824 floats
    float* zbuf = wsf + 4 * 589824;       // 294912
    float* mbuf = zbuf + 294912;          // 294912
    float* WcTr = mbuf + 294912;          // 36864-float region (bf16 uses half)
    float* imgTr = WcTr + 36864;          // 8388608-float region

    __hip_bfloat16* WcPk  = (__hip_bfloat16*)WcTr;
    ushort*         imgTb = (ushort*)imgTr;   // bf16 imgT

    // Wpk/bpack/osT ALIAS the imgT region (conv pipeline finishes before
    // transpose_kernel overwrites imgT — same-stream serialization).
    __hip_bfloat16* Wpk   = (__hip_bfloat16*)imgTr;            // 153600 bf16
    float*          bpack = imgTr + 76800;                     // 96 f32
    __hip_bfloat16* osT   = (__hip_bfloat16*)(imgTr + 76912);  // 2230272 bf16

    packw_kernel<<<dim3((96 * 1600 + 255) / 256), 256, 0, stream>>>(
        w_pc1, b_pc1, w_pc2, b_pc2, w_pc4, b_pc4, w_pc5, b_pc5,
        w_z, b_z, w_m, b_m, Wpk, bpack);
    packosT_kernel<<<dim3(132, 2), 256, 0, stream>>>(osrc, osT);
    conv_mfma_kernel<<<dim3(128, 2, 3), 256, 0, stream>>>(
        Wpk, bpack, osT, offs, zbuf, mbuf);
    transpose_kernel<<<dim3(256, 2, 4), 256, 0, stream>>>(img1, img2, img4, img5, imgTb);
    wcpk_kernel<<<dim3(144), 256, 0, stream>>>(w_cv, WcPk);
    fused_kernel<<<dim3(2048), 256, 0, stream>>>(offs, zbuf, mbuf, imgTb, WcPk, out);
}

// Round 11
// 116.830 us; speedup vs baseline: 1.9880x; 1.3935x over previous
//
#include <hip/hip_runtime.h>
#include <hip/hip_bf16.h>
#include <math.h>

#define HWX 16384   // 128*128 pixels per (b, channel) plane

typedef __attribute__((ext_vector_type(8))) short short8v;
typedef __attribute__((ext_vector_type(4))) float f32x4;

__device__ inline ushort f2bf(float x) {
    union { __hip_bfloat16 h; ushort u; } cv;
    cv.h = __float2bfloat16(x);
    return cv.u;
}

// ---------------------------------------------------------------------------
// Pack six 5x5-conv weight sets -> Wpk[oc][k] bf16, k = (ky*5+kx)*64 + ic.
//   oc 0..17 pc1 | 18..35 pc2 | 36..53 pc4 | 54..71 pc5 | 72..80 z | 81..89 m
//   | 90..95 zero.  bias fp32 in bpack[96].  Source OIHW: o*1600 + ic*25 + kyx.
// ---------------------------------------------------------------------------
__global__ __launch_bounds__(256) void packw_kernel(
    const float* __restrict__ w1, const float* __restrict__ b1,
    const float* __restrict__ w2, const float* __restrict__ b2,
    const float* __restrict__ w4, const float* __restrict__ b4,
    const float* __restrict__ w5, const float* __restrict__ b5,
    const float* __restrict__ wz, const float* __restrict__ bz,
    const float* __restrict__ wm, const float* __restrict__ bm,
    __hip_bfloat16* __restrict__ Wpk, float* __restrict__ bpack)
{
    const int idx = blockIdx.x * 256 + threadIdx.x;
    if (idx < 96) {
        const int o = idx; float v = 0.f;
        if      (o < 18) v = b1[o];
        else if (o < 36) v = b2[o - 18];
        else if (o < 54) v = b4[o - 36];
        else if (o < 72) v = b5[o - 54];
        else if (o < 81) v = bz[o - 72];
        else if (o < 90) v = bm[o - 81];
        bpack[o] = v;
    }
    if (idx < 96 * 1600) {
        const int o   = idx / 1600;
        const int k   = idx - o * 1600;
        const int kyx = k >> 6;
        const int ic  = k & 63;
        const int off = ic * 25 + kyx;
        float v = 0.f;
        if      (o < 18) v = w1[o * 1600 + off];
        else if (o < 36) v = w2[(o - 18) * 1600 + off];
        else if (o < 54) v = w4[(o - 36) * 1600 + off];
        else if (o < 72) v = w5[(o - 54) * 1600 + off];
        else if (o < 81) v = wz[(o - 72) * 1600 + off];
        else if (o < 90) v = wm[(o - 81) * 1600 + off];
        Wpk[idx] = __float2bfloat16(v);
    }
}

// ---------------------------------------------------------------------------
// offset_source -> channel-last bf16 with baked-in zero pad ring:
//   osT[b][yy:132][xx:132][c:64]
// ---------------------------------------------------------------------------
__global__ __launch_bounds__(256) void packosT_kernel(
    const float* __restrict__ src, __hip_bfloat16* __restrict__ osT)
{
    const int yy = blockIdx.x;
    const int b  = blockIdx.y;
    __hip_bfloat16* dst = osT + ((size_t)b * 132 + yy) * 132 * 64;
    for (int idx = threadIdx.x; idx < 132 * 64; idx += 256) {
        const int xx = idx >> 6;
        const int c  = idx & 63;
        float v = 0.f;
        if (yy >= 2 && yy < 130 && xx >= 2 && xx < 130)
            v = src[(((b << 6) + c) << 14) + ((yy - 2) << 7) + (xx - 2)];
        dst[idx] = __float2bfloat16(v);
    }
}

// ---------------------------------------------------------------------------
// MFMA conv, 2-phase LDS-staged GEMM (r8-r10: register-destination load
// pipelines are always collapsed by the backend; global_load_lds DMA cannot
// be sunk). Block = 96oc x 64px, 4 waves of 48oc x 32px.
//  - B slab (osT rows y..y+4, 68 cols, 64ch = 43.5KB) staged ONCE, reg->LDS,
//    ch-block XOR swizzle (cb^(col&7)) => ds_read_b128 2-way (free).
//  - W K-step tile (96oc x 64ic = 12KB) double-buffered global_load_lds,
//    linear LDS dest + pre-swizzled source (cb^(oc&7)), read with same XOR.
// grid (256, 2b), 25 K-steps, one barrier per step.
// ---------------------------------------------------------------------------
__global__ __launch_bounds__(256) void conv_mfma_kernel(
    const __hip_bfloat16* __restrict__ Wpk,   // [96][1600]
    const float* __restrict__ bpack,          // [96]
    const __hip_bfloat16* __restrict__ osT,   // [2][132][132][64]
    float* __restrict__ offs,                 // [4][2][18][HWX]
    float* __restrict__ zbuf,                 // [2][9][HWX]
    float* __restrict__ mbuf)                 // [2][9][HWX]
{
    __shared__ __align__(16) ushort slab[5 * 68 * 64];    // 43520 B
    __shared__ __align__(16) ushort wbuf[2][96 * 64];     // 2 x 12288 B

    const int bx = blockIdx.x;
    const int y  = bx >> 1;
    const int x0 = (bx & 1) << 6;
    const int b  = blockIdx.y;
    const int t    = threadIdx.x;
    const int wv   = t >> 6;
    const int lane = t & 63;
    const int l15  = lane & 15;
    const int kgrp = lane >> 4;
    const int wm   = wv >> 1;      // 0..1 -> 48-oc half
    const int wn   = wv & 1;       // 0..1 -> 32-px half

    const ushort* ob = (const ushort*)osT + (size_t)b * (132 * 132 * 64);
    const ushort* Wg = (const ushort*)Wpk;

    // ---- stage B slab (reg->LDS, swizzled ds_write) ----
    for (int c = t; c < 2720; c += 256) {          // 5*68*8 chunks of 16B
        const int r5  = c / 544;                   // 68*8
        const int rem = c - r5 * 544;
        const int col = rem >> 3;
        const int cb  = rem & 7;
        const short8v v = *(const short8v*)(ob + (((y + r5) * 132 + x0 + col) << 6) + (cb << 3));
        const int slot = r5 * 544 + (col << 3) + (cb ^ (col & 7));
        *(short8v*)((char*)slab + slot * 16) = v;
    }

    // ---- W stage macro: 768 16B chunks, 3 per thread, linear LDS dest ----
#define STAGE_W(kyx, bi)                                                       \
    _Pragma("unroll")                                                          \
    for (int it = 0; it < 3; ++it) {                                           \
        const int c  = it * 256 + t;                                           \
        const int oc = c >> 3, cb = c & 7;                                     \
        const ushort* src = Wg + oc * 1600 + (kyx) * 64 + ((cb ^ (oc & 7)) << 3); \
        __builtin_amdgcn_global_load_lds(                                      \
            (const __attribute__((address_space(1))) void*)src,                \
            (__attribute__((address_space(3))) void*)((char*)wbuf[bi] + (it * 256 + wv * 64) * 16), \
            16, 0, 0);                                                         \
    }

    STAGE_W(0, 0)
    __syncthreads();   // drains vmcnt (W0) + lgkm (slab writes)

    f32x4 acc[3][2];
    #pragma unroll
    for (int m = 0; m < 3; ++m)
        #pragma unroll
        for (int n = 0; n < 2; ++n) acc[m][n] = (f32x4){0.f, 0.f, 0.f, 0.f};

    for (int kyx = 0; kyx < 25; ++kyx) {
        const int bi = kyx & 1;
        if (kyx < 24) STAGE_W(kyx + 1, bi ^ 1)
        const int ky = kyx / 5, kx = kyx % 5;
        #pragma unroll
        for (int kc = 0; kc < 2; ++kc) {
            const int kcg = (kc << 2) + kgrp;
            short8v af[3], bf[2];
            #pragma unroll
            for (int m = 0; m < 3; ++m) {
                const int oc = wm * 48 + m * 16 + l15;
                af[m] = *(const short8v*)((char*)wbuf[bi] + ((oc << 3) + (kcg ^ (oc & 7))) * 16);
            }
            #pragma unroll
            for (int n = 0; n < 2; ++n) {
                const int col = wn * 32 + n * 16 + l15 + kx;
                bf[n] = *(const short8v*)((char*)slab + ((ky * 68 + col) * 8 + (kcg ^ (col & 7))) * 16);
            }
            #pragma unroll
            for (int m = 0; m < 3; ++m)
                #pragma unroll
                for (int n = 0; n < 2; ++n)
                    acc[m][n] = __builtin_amdgcn_mfma_f32_16x16x32_bf16(af[m], bf[n], acc[m][n], 0, 0, 0);
        }
        __syncthreads();   // vmcnt drain = next W tile ready; wbuf reuse safe
    }
#undef STAGE_W

    // ---- epilogue: bias + activation + scatter ----
    #pragma unroll
    for (int m = 0; m < 3; ++m) {
        const int ocb = wm * 48 + m * 16 + (kgrp << 2);
        #pragma unroll
        for (int n = 0; n < 2; ++n) {
            const int x = x0 + wn * 32 + n * 16 + l15;
            const int p = (y << 7) + x;
            #pragma unroll
            for (int r = 0; r < 4; ++r) {
                const int o = ocb + r;
                const float v = acc[m][n][r] + bpack[o];
                if (o < 72) {
                    const int i = o / 18, ch = o - i * 18;
                    offs[i * (2 * 18 * HWX) + (((b * 18) + ch) << 14) + p] = v;
                } else if (o < 81) {
                    zbuf[((b * 9 + (o - 72)) << 14) + p] = 3.f / (1.f + expf(-v));
                } else if (o < 90) {
                    mbuf[((b * 9 + (o - 81)) << 14) + p] = 1.f / (1.f + expf(-v));
                }
            }
        }
    }
}

// ---------------------------------------------------------------------------
// Transpose img[b,c,y,x] fp32 -> imgT[img][b][p][c] bf16 (channel-last).
// ---------------------------------------------------------------------------
__global__ __launch_bounds__(256) void transpose_kernel(
    const float* __restrict__ i0, const float* __restrict__ i1,
    const float* __restrict__ i2, const float* __restrict__ i3,
    ushort* __restrict__ imgT)
{
    const int img = blockIdx.z;
    const int b   = blockIdx.y;
    const int p0  = blockIdx.x << 6;
    const float* src = (img == 0) ? i0 : (img == 1) ? i1 : (img == 2) ? i2 : i3;

    __shared__ float tile[64][65];
    const int t = threadIdx.x;
    const int pp = t & 63, c0 = t >> 6;
    #pragma unroll
    for (int k = 0; k < 16; ++k) {
        const int c = (k << 2) + c0;
        tile[c][pp] = src[(((b << 6) + c) << 14) + p0 + pp];
    }
    __syncthreads();
    const int c2 = t & 31, pl = t >> 5;
    #pragma unroll
    for (int k = 0; k < 8; ++k) {
        const int pi = (k << 3) + pl;
        const uint packed = (uint)f2bf(tile[2 * c2][pi])
                          | ((uint)f2bf(tile[2 * c2 + 1][pi]) << 16);
        *(uint*)(imgT + ((size_t)(((img << 1) + b) << 14) + p0 + pi) * 64 + 2 * c2)
            = packed;
    }
}

// ---------------------------------------------------------------------------
// WcPk = flat bf16 cast of w_conv[64][64][9]  (A-operand layout [oc][cn]).
// ---------------------------------------------------------------------------
__global__ __launch_bounds__(256) void wcpk_kernel(
    const float* __restrict__ wc, __hip_bfloat16* __restrict__ WcPk)
{
    const int idx = blockIdx.x * 256 + threadIdx.x;
    if (idx < 36864) WcPk[idx] = __float2bfloat16(wc[idx]);
}

// ---------------------------------------------------------------------------
// Fused deform-sample + weighted-sum + MFMA contraction.
// One block = 16 consecutive pixels of one row of one batch.
// ---------------------------------------------------------------------------
__global__ __launch_bounds__(256, 4) void fused_kernel(
    const float* __restrict__ offs,   // [4][2][18][HWX]
    const float* __restrict__ zbuf,   // [2][9][HWX]
    const float* __restrict__ mbuf,   // [2][9][HWX]
    const ushort* __restrict__ imgT,  // [4][2][HWX][64] bf16
    const __hip_bfloat16* __restrict__ WcPk,  // [64][576]
    float* __restrict__ out)          // [2][64][HWX]
{
    __shared__ __hip_bfloat16 s_sb[16 * 584];   // 18688 B
    __shared__ int4   s_ti4[16 * 36];           // 9216 B  (byte offsets)
    __shared__ float4 s_tw4[16 * 36];           // 9216 B

    const int t   = threadIdx.x;
    const int pid = blockIdx.x;
    const int b   = pid >> 10;
    const int rem = pid & 1023;
    const int h   = rem >> 3;
    const int w0p = (rem & 7) << 4;

    // ---- phase A: taps (ti stored as byte offset = pixel*128) ----
    for (int u = t; u < 576; u += 256) {
        const int px   = u / 36;
        const int unit = u - px * 36;
        const int i    = unit / 9;
        const int n    = unit - i * 9;
        const int wcol = w0p + px;
        const int p    = (h << 7) + wcol;

        const float* ob = offs + i * (2 * 18 * HWX) + ((b * 18) << 14);
        const float ox = ob[(n << 14) + p];
        const float oy = ob[((n + 9) << 14) + p];
        const float z  = zbuf[((b * 9 + n) << 14) + p];
        const float mm = mbuf[((b * 9 + n) << 14) + p];

        const float zc0 = (i == 0) ? 1.f : 0.f;
        const float zc1 = (i == 0) ? (-11.f / 6.f) : (i == 1) ? 3.f
                         : (i == 2) ? -1.5f : (1.f / 3.f);
        const float zc2 = (i == 0) ? 1.f : (i == 1) ? -2.5f
                         : (i == 2) ? 2.f : -0.5f;
        const float zc3 = (i == 0) ? (-1.f / 6.f) : (i == 1) ? 0.5f
                         : (i == 2) ? -0.5f : (1.f / 6.f);
        const float zw   = zc0 + z * (zc1 + z * (zc2 + z * zc3));
        const float coef = zw * mm;

        const float pxf = (float)(h + n / 3) + ox;
        const float pyf = (float)(wcol + n % 3) + oy;
        const float flx = floorf(pxf), fly = floorf(pyf);
        const float qltx = fminf(fmaxf(flx, 0.f), 129.f);
        const float qrbx = fminf(fmaxf(flx + 1.f, 0.f), 129.f);
        const float qlty = fminf(fmaxf(fly, 0.f), 129.f);
        const float qrby = fminf(fmaxf(fly + 1.f, 0.f), 129.f);
        const float pxc = fminf(fmaxf(pxf, 0.f), 129.f);
        const float pyc = fminf(fmaxf(pyf, 0.f), 129.f);
        const float gxl = 1.f + (qltx - pxc);
        const float gxr = 1.f - (qrbx - pxc);
        const float gyl = 1.f + (qlty - pyc);
        const float gyr = 1.f - (qrby - pyc);
        const int ixl = (int)qltx, ixr = (int)qrbx;
        const int iyl = (int)qlty, iyr = (int)qrby;

        int4 ti; float4 tw;
        auto mk = [&](int qx, int qy, float g, int& ii, float& ww) {
            const bool valid = (qx >= 1) && (qx <= 128) && (qy >= 1) && (qy <= 128);
            ii = valid ? (((qx - 1) << 14) + ((qy - 1) << 7)) : 0;  // byte offset
            ww = valid ? g * coef : 0.f;
        };
        mk(ixl, iyl, gxl * gyl, ti.x, tw.x);
        mk(ixr, iyr, gxr * gyr, ti.y, tw.y);
        mk(ixr, iyl, gxr * gyl, ti.z, tw.z);
        mk(ixl, iyr, gxl * gyr, ti.w, tw.w);
        s_ti4[u] = ti;
        s_tw4[u] = tw;
    }
    __syncthreads();

    // ---- phase B: wide gather (uniform base + 32-bit voffset) ----
    const int lane = t & 63;
    const int wv   = t >> 6;
    const int c4   = lane & 15;
    const int pxs  = lane >> 4;
    const int px   = (wv << 2) + pxs;
    const int laneByte = c4 << 3;   // 4 channels * 2B

    f32x4 s4[9];
    #pragma unroll
    for (int n = 0; n < 9; ++n) s4[n] = (f32x4){0.f, 0.f, 0.f, 0.f};

    const int tb = px * 36;
    #pragma unroll 1
    for (int i = 0; i < 4; ++i) {
        const char* ib = (const char*)(imgT + (((size_t)((i << 1) + b)) << 20));
        #pragma unroll
        for (int n = 0; n < 9; ++n) {
            const int4   tib = s_ti4[tb + i * 9 + n];
            const float4 tw  = s_tw4[tb + i * 9 + n];
            {
                const uint2 v = *(const uint2*)(ib + (tib.x + laneByte));
                s4[n].x = fmaf(tw.x, __uint_as_float(v.x << 16),         s4[n].x);
                s4[n].y = fmaf(tw.x, __uint_as_float(v.x & 0xffff0000u), s4[n].y);
                s4[n].z = fmaf(tw.x, __uint_as_float(v.y << 16),         s4[n].z);
                s4[n].w = fmaf(tw.x, __uint_as_float(v.y & 0xffff0000u), s4[n].w);
            }
            {
                const uint2 v = *(const uint2*)(ib + (tib.y + laneByte));
                s4[n].x = fmaf(tw.y, __uint_as_float(v.x << 16),         s4[n].x);
                s4[n].y = fmaf(tw.y, __uint_as_float(v.x & 0xffff0000u), s4[n].y);
                s4[n].z = fmaf(tw.y, __uint_as_float(v.y << 16),         s4[n].z);
                s4[n].w = fmaf(tw.y, __uint_as_float(v.y & 0xffff0000u), s4[n].w);
            }
            {
                const uint2 v = *(const uint2*)(ib + (tib.z + laneByte));
                s4[n].x = fmaf(tw.z, __uint_as_float(v.x << 16),         s4[n].x);
                s4[n].y = fmaf(tw.z, __uint_as_float(v.x & 0xffff0000u), s4[n].y);
                s4[n].z = fmaf(tw.z, __uint_as_float(v.y << 16),         s4[n].z);
                s4[n].w = fmaf(tw.z, __uint_as_float(v.y & 0xffff0000u), s4[n].w);
            }
            {
                const uint2 v = *(const uint2*)(ib + (tib.w + laneByte));
                s4[n].x = fmaf(tw.w, __uint_as_float(v.x << 16),         s4[n].x);
                s4[n].y = fmaf(tw.w, __uint_as_float(v.x & 0xffff0000u), s4[n].y);
                s4[n].z = fmaf(tw.w, __uint_as_float(v.y << 16),         s4[n].z);
                s4[n].w = fmaf(tw.w, __uint_as_float(v.y & 0xffff0000u), s4[n].w);
            }
            if (n == 2 || n == 5) __builtin_amdgcn_sched_barrier(0);
        }
        __builtin_amdgcn_sched_barrier(0);
    }

    // pack to bf16 pairs, write 9 contiguous uint2 (cn = (4*c4+j)*9 + n)
    uint bufu[18];
    #pragma unroll
    for (int k = 0; k < 18; ++k) {
        const int u0 = 2 * k, u1 = 2 * k + 1;
        const float v0 = s4[u0 % 9][u0 / 9];
        const float v1 = s4[u1 % 9][u1 / 9];
        bufu[k] = (uint)f2bf(v0) | ((uint)f2bf(v1) << 16);
    }
    {
        uint2* dst = (uint2*)((char*)s_sb + px * 1168 + c4 * 72);
        #pragma unroll
        for (int k = 0; k < 9; ++k)
            dst[k] = ((const uint2*)bufu)[k];
    }
    __syncthreads();

    // ---- phase C: MFMA contraction, wave wv -> oc block wv*16 ----
    const int l15  = lane & 15;
    const int kgrp = lane >> 4;
    const ushort* Wb = (const ushort*)WcPk + (wv * 16 + l15) * 576 + kgrp * 8;
    const ushort* sb = (const ushort*)s_sb + l15 * 584 + kgrp * 8;

    f32x4 acc = {0.f, 0.f, 0.f, 0.f};
    #pragma unroll
    for (int ks = 0; ks < 18; ++ks) {
        const short8v a  = *(const short8v*)(Wb + ks * 32);
        const short8v bb = *(const short8v*)(sb + ks * 32);
        acc = __builtin_amdgcn_mfma_f32_16x16x32_bf16(a, bb, acc, 0, 0, 0);
    }

    const int p = (h << 7) + w0p + l15;
    #pragma unroll
    for (int r = 0; r < 4; ++r) {
        const int oc = wv * 16 + (kgrp << 2) + r;
        out[(((b << 6) + oc) << 14) + p] = acc[r];
    }
}

// ---------------------------------------------------------------------------
extern "C" void kernel_launch(void* const* d_in, const int* in_sizes, int n_in,
                              void* d_out, int out_size, void* d_ws, size_t ws_size,
                              hipStream_t stream) {
    (void)in_sizes; (void)n_in; (void)out_size; (void)ws_size;
    const float* img1  = (const float*)d_in[0];
    const float* img2  = (const float*)d_in[1];
    const float* img4  = (const float*)d_in[2];
    const float* img5  = (const float*)d_in[3];
    const float* osrc  = (const float*)d_in[4];
    const float* w_pc1 = (const float*)d_in[5];
    const float* b_pc1 = (const float*)d_in[6];
    const float* w_pc2 = (const float*)d_in[7];
    const float* b_pc2 = (const float*)d_in[8];
    const float* w_pc4 = (const float*)d_in[9];
    const float* b_pc4 = (const float*)d_in[10];
    const float* w_pc5 = (const float*)d_in[11];
    const float* b_pc5 = (const float*)d_in[12];
    const float* w_z   = (const float*)d_in[13];
    const float* b_z   = (const float*)d_in[14];
    const float* w_m   = (const float*)d_in[15];
    const float* b_m   = (const float*)d_in[16];
    const float* w_cv  = (const float*)d_in[17];
    float* out = (float*)d_out;

    float* wsf  = (float*)d_ws;
    float* offs = wsf;                    // 4 * 589824 floats
    float* zbuf = wsf + 4 * 589824;       // 294912
    float* mbuf = zbuf + 294912;          // 294912
    float* WcTr = mbuf + 294912;          // 36864-float region (bf16 uses half)
    float* imgTr = WcTr + 36864;          // 8388608-float region

    __hip_bfloat16* WcPk  = (__hip_bfloat16*)WcTr;
    ushort*         imgTb = (ushort*)imgTr;   // bf16 imgT

    // Wpk/bpack/osT ALIAS the imgT region (conv pipeline finishes before
    // transpose_kernel overwrites imgT — same-stream serialization).
    __hip_bfloat16* Wpk   = (__hip_bfloat16*)imgTr;            // 153600 bf16
    float*          bpack = imgTr + 76800;                     // 96 f32
    __hip_bfloat16* osT   = (__hip_bfloat16*)(imgTr + 76912);  // 2230272 bf16

    packw_kernel<<<dim3((96 * 1600 + 255) / 256), 256, 0, stream>>>(
        w_pc1, b_pc1, w_pc2, b_pc2, w_pc4, b_pc4, w_pc5, b_pc5,
        w_z, b_z, w_m, b_m, Wpk, bpack);
    packosT_kernel<<<dim3(132, 2), 256, 0, stream>>>(osrc, osT);
    conv_mfma_kernel<<<dim3(256, 2), 256, 0, stream>>>(
        Wpk, bpack, osT, offs, zbuf, mbuf);
    transpose_kernel<<<dim3(256, 2, 4), 256, 0, stream>>>(img1, img2, img4, img5, imgTb);
    wcpk_kernel<<<dim3(144), 256, 0, stream>>>(w_cv, WcPk);
    fused_kernel<<<dim3(2048), 256, 0, stream>>>(offs, zbuf, mbuf, imgTb, WcPk, out);
}